// Round 4
// baseline (179.317 us; speedup 1.0000x reference)
//
#include <hip/hip_runtime.h>
#include <hip/hip_bf16.h>

// UnifiedAttention: x->QKV gemm -> causal MHA (H=16,D=64) -> proj gemm
// B=2, N=2048, C=1024. bf16 MFMA with fp32 accum throughout.

typedef __bf16 bf16x8 __attribute__((ext_vector_type(8)));
typedef __bf16 bf16x4 __attribute__((ext_vector_type(4)));
typedef __bf16 bf16x2 __attribute__((ext_vector_type(2)));
typedef float  f32x4  __attribute__((ext_vector_type(4)));
typedef float  f32x16 __attribute__((ext_vector_type(16)));
typedef int    i32x4  __attribute__((ext_vector_type(4)));

#define MFMA16(a, b, c) __builtin_amdgcn_mfma_f32_16x16x32_bf16((a), (b), (c), 0, 0, 0)
#define MFMA32(a, b, c) __builtin_amdgcn_mfma_f32_32x32x16_bf16((a), (b), (c), 0, 0, 0)

__device__ __forceinline__ void async_copy16(const __bf16* g, __bf16* l) {
    __builtin_amdgcn_global_load_lds(
        (const __attribute__((address_space(1))) void*)g,
        (__attribute__((address_space(3))) void*)l,
        16, 0, 0);
}

__device__ __forceinline__ unsigned packbf(float a, float b) {
    union { bf16x2 v; unsigned u; } un;
    un.v[0] = (__bf16)a; un.v[1] = (__bf16)b;
    return un.u;
}

// ---------------- fp32 -> bf16 conversion (vectorized) ----------------
__global__ void f32_to_bf16_k(const float* __restrict__ in, __bf16* __restrict__ out, int n4) {
    int i = blockIdx.x * blockDim.x + threadIdx.x;
    if (i >= n4) return;
    float4 v = reinterpret_cast<const float4*>(in)[i];
    bf16x4 o;
    o[0] = (__bf16)v.x; o[1] = (__bf16)v.y; o[2] = (__bf16)v.z; o[3] = (__bf16)v.w;
    reinterpret_cast<bf16x4*>(out)[i] = o;
}

// ---------------- mask tile reduction: 64x64 tiles -> all-ones flag ----------------
__global__ void mask_reduce_k(const int* __restrict__ mask, int* __restrict__ mflag) {
    __shared__ int ok;
    const int t = threadIdx.x;
    if (t == 0) ok = 1;
    __syncthreads();
    const int jt = blockIdx.x & 31;
    const int it = (blockIdx.x >> 5) & 31;
    const int b  = blockIdx.x >> 10;
    bool all1 = true;
#pragma unroll
    for (int c = 0; c < 4; ++c) {
        const int row = c * 16 + (t >> 4);
        const int col = (t & 15) * 4;
        const int4 v = *reinterpret_cast<const int4*>(
            &mask[((size_t)(b * 2048 + it * 64 + row)) * 2048 + jt * 64 + col]);
        all1 = all1 && v.x && v.y && v.z && v.w;
    }
    if (!all1) ok = 0;
    __syncthreads();
    if (t == 0) mflag[(b * 32 + it) * 32 + jt] = ok;
}

// ============ 8-phase 256x256 QKV GEMM (T1+T2+T3+T4+T5), K=1024 =================
#define BAR() asm volatile("s_barrier" ::: "memory")
#define VM2() asm volatile("s_waitcnt vmcnt(2)" ::: "memory")

__global__ __launch_bounds__(512, 2) void gemm_qkv8_k(
    const __bf16* __restrict__ A, const __bf16* __restrict__ Bm,
    const float* __restrict__ bias,
    __bf16* __restrict__ qg, __bf16* __restrict__ kg, __bf16* __restrict__ vtg)
{
    __shared__ __align__(16) __bf16 As[2][16384];   // [buf][256 rows x 64]
    __shared__ __align__(16) __bf16 Bs[2][16384];

    const int t = threadIdx.x;
    const int lane = t & 63;
    const int w = t >> 6;
    const int wr = w >> 2, wc = w & 3;
    const int li = lane & 15, g = lane >> 4;

    // XCD-aware bijective swizzle (grid=192, 192%8==0, 24 blocks per XCD)
    const int bid = (blockIdx.x & 7) * 24 + (blockIdx.x >> 3);
    const int m0 = (bid / 12) << 8;     // N tiles = 3072/256 = 12
    const int n0 = (bid % 12) << 8;

    const int srow = t >> 3;
    const int scol = ((t & 7) ^ (srow & 7)) << 3;
    const __bf16* pA = A  + (size_t)(m0 + srow) * 1024 + scol;
    const __bf16* pB = Bm + (size_t)(n0 + srow) * 1024 + scol;
    __bf16* dA = &As[0][0] + t * 8;
    __bf16* dB = &Bs[0][0] + t * 8;

#define STAGE_A(BB, T, HH) do {                                                   \
    const size_t ro_ = (size_t)((HH) * 128) * 1024 + (size_t)(T) * 64;            \
    async_copy16(pA + ro_,         dA + (BB) * 16384 + (HH) * 8192);              \
    async_copy16(pA + ro_ + 65536, dA + (BB) * 16384 + (HH) * 8192 + 4096);       \
  } while (0)
#define STAGE_B(BB, T, HH) do {                                                   \
    const size_t ro_ = (size_t)((HH) * 128) * 1024 + (size_t)(T) * 64;            \
    async_copy16(pB + ro_,         dB + (BB) * 16384 + (HH) * 8192);              \
    async_copy16(pB + ro_ + 65536, dB + (BB) * 16384 + (HH) * 8192 + 4096);       \
  } while (0)

    const int aoff0 = ((0 + g) ^ (li & 7)) << 3;
    const int aoff1 = ((4 + g) ^ (li & 7)) << 3;
    const int abase = (wr * 128 + li) * 64;
    const int bbase = (wc * 64 + li) * 64;

    f32x4 acc[8][4] = {};
    bf16x8 a[4][2], b[2][2][2];

#define READ_A(BB, MH) do { _Pragma("unroll")                                     \
    for (int mi2 = 0; mi2 < 4; ++mi2) {                                           \
      const __bf16* p_ = &As[BB][abase + ((MH) * 4 + mi2) * 1024];                \
      a[mi2][0] = *reinterpret_cast<const bf16x8*>(p_ + aoff0);                   \
      a[mi2][1] = *reinterpret_cast<const bf16x8*>(p_ + aoff1); } } while (0)
#define READ_B(BB, NH) do { _Pragma("unroll")                                     \
    for (int ni2 = 0; ni2 < 2; ++ni2) {                                           \
      const __bf16* p_ = &Bs[BB][bbase + ((NH) * 2 + ni2) * 1024];                \
      b[NH][ni2][0] = *reinterpret_cast<const bf16x8*>(p_ + aoff0);               \
      b[NH][ni2][1] = *reinterpret_cast<const bf16x8*>(p_ + aoff1); } } while (0)
#define MFMA_QUAD(MH, NH) do {                                                    \
    __builtin_amdgcn_s_setprio(1);                                                \
    _Pragma("unroll") for (int mi2 = 0; mi2 < 4; ++mi2)                           \
    _Pragma("unroll") for (int ni2 = 0; ni2 < 2; ++ni2) {                         \
      f32x4 c_ = acc[(MH) * 4 + mi2][(NH) * 2 + ni2];                             \
      c_ = MFMA16(a[mi2][0], b[NH][ni2][0], c_);                                  \
      c_ = MFMA16(a[mi2][1], b[NH][ni2][1], c_);                                  \
      acc[(MH) * 4 + mi2][(NH) * 2 + ni2] = c_; }                                 \
    __builtin_amdgcn_s_setprio(0); } while (0)

#define KTILE(BB, T) do {                                                         \
    const int Tn_  = ((T) + 1 < 16) ? (T) + 1 : 15;                               \
    const int Tn2_ = ((T) + 2 < 16) ? (T) + 2 : 15;                               \
    STAGE_A((BB) ^ 1, Tn_, 1);                                                    \
    READ_A(BB, 0); READ_B(BB, 0);                                                 \
    BAR(); MFMA_QUAD(0, 0); BAR();                                                \
    STAGE_B((BB) ^ 1, Tn_, 0);                                                    \
    READ_B(BB, 1);                                                                \
    BAR(); MFMA_QUAD(0, 1); BAR();                                                \
    STAGE_B((BB) ^ 1, Tn_, 1);                                                    \
    READ_A(BB, 1);                                                                \
    BAR(); MFMA_QUAD(1, 0); BAR();                                                \
    STAGE_A((BB), Tn2_, 0);                                                       \
    VM2(); BAR(); MFMA_QUAD(1, 1); BAR();                                         \
  } while (0)

    STAGE_A(0, 0, 0); STAGE_A(0, 0, 1);
    STAGE_B(0, 0, 0); STAGE_B(0, 0, 1);
    STAGE_A(1, 1, 0);
    VM2(); BAR();

#pragma unroll 1
    for (int jj = 0; jj < 8; ++jj) {
        KTILE(0, 2 * jj);
        KTILE(1, 2 * jj + 1);
    }

    // ---- epilogue: scatter into q (scaled by 0.125*log2e for exp2 softmax) / k / vT
    const int nbase = n0 + wc * 64;
    const int s = nbase >> 10;
    const int headg = (m0 >> 11) * 16 + ((nbase & 1023) >> 6);
    const int mrow = (m0 & 2047) + wr * 128 + g * 4;
    float bv[4];
#pragma unroll
    for (int ni = 0; ni < 4; ++ni) bv[ni] = bias[nbase + ni * 16 + li];

    if (s == 2) {
#pragma unroll
        for (int mi = 0; mi < 8; ++mi) {
#pragma unroll
            for (int ni = 0; ni < 4; ++ni) {
                bf16x4 st;
#pragma unroll
                for (int r = 0; r < 4; ++r) st[r] = (__bf16)(acc[mi][ni][r] + bv[ni]);
                *reinterpret_cast<bf16x4*>(
                    &vtg[((size_t)(headg * 64) + ni * 16 + li) * 2048 + mrow + mi * 16]) = st;
            }
        }
    } else {
        __bf16* og = (s == 0) ? qg : kg;
        const float sc = (s == 0) ? 0.18033688f : 1.0f;   // 0.125 * log2(e)
#pragma unroll
        for (int mi = 0; mi < 8; ++mi) {
#pragma unroll
            for (int r = 0; r < 4; ++r) {
                __bf16* rp = og + ((size_t)headg * 2048 + mrow + mi * 16 + r) * 64;
#pragma unroll
                for (int ni = 0; ni < 4; ++ni)
                    rp[ni * 16 + li] = (__bf16)((acc[mi][ni][r] + bv[ni]) * sc);
            }
        }
    }
#undef KTILE
#undef MFMA_QUAD
#undef READ_A
#undef READ_B
#undef STAGE_A
#undef STAGE_B
}

// ---------------- 2-phase 128x128 GEMM (proj): C = A*Bm^T + bias, fp32 out -------
__global__ __launch_bounds__(256) void gemm_proj_k(
    const __bf16* __restrict__ A, const __bf16* __restrict__ Bm,
    const float* __restrict__ bias, int M, int N, int K,
    float* __restrict__ outf)
{
    __shared__ __align__(16) __bf16 As[128 * 64];
    __shared__ __align__(16) __bf16 Bs[128 * 64];
    const int t = threadIdx.x;
    const int nb = N >> 7;
    const int m0 = (blockIdx.x / nb) << 7;
    const int n0 = (blockIdx.x % nb) << 7;
    const int lane = t & 63, w = t >> 6;
    const int g = lane >> 4, li = lane & 15;
    const int wr = w >> 1, wc = w & 1;
    const __bf16* Ab = A + (size_t)m0 * K;
    const __bf16* Bb = Bm + (size_t)n0 * K;

    f32x4 acc[4][4] = {};

    for (int k0 = 0; k0 < K; k0 += 64) {
#pragma unroll
        for (int c = 0; c < 4; ++c) {
            const int e = (c * 256 + t) * 8;
            const int row = e >> 6;
            const int col = e & 63;
            async_copy16(Ab + (size_t)row * K + k0 + col, As + e);
            async_copy16(Bb + (size_t)row * K + k0 + col, Bs + e);
        }
        __syncthreads();
#pragma unroll
        for (int kk = 0; kk < 2; ++kk) {
            bf16x8 af[4], bf[4];
#pragma unroll
            for (int mi = 0; mi < 4; ++mi)
                af[mi] = *reinterpret_cast<const bf16x8*>(
                    &As[(wr * 64 + mi * 16 + li) * 64 + kk * 32 + g * 8]);
#pragma unroll
            for (int ni = 0; ni < 4; ++ni)
                bf[ni] = *reinterpret_cast<const bf16x8*>(
                    &Bs[(wc * 64 + ni * 16 + li) * 64 + kk * 32 + g * 8]);
#pragma unroll
            for (int mi = 0; mi < 4; ++mi)
#pragma unroll
                for (int ni = 0; ni < 4; ++ni)
                    acc[mi][ni] = MFMA16(af[mi], bf[ni], acc[mi][ni]);
        }
        __syncthreads();
    }

#pragma unroll
    for (int mi = 0; mi < 4; ++mi) {
#pragma unroll
        for (int ni = 0; ni < 4; ++ni) {
            const int n = n0 + wc * 64 + ni * 16 + li;
            const float bv = bias[n];
#pragma unroll
            for (int r = 0; r < 4; ++r) {
                const int m = m0 + wr * 64 + mi * 16 + g * 4 + r;
                outf[(size_t)m * N + n] = acc[mi][ni][r] + bv;
            }
        }
    }
}

// ---------------- flash attention, causal: barrier-free, direct-L2 K/V -----------
// q:[BH,2048,64] (scale*log2e prefolded), k:[BH,2048,64], vT:[BH,64,2048] bf16.
// 4 independent waves x 32 queries per block (no LDS, no __syncthreads).
// Swapped QK^T (mfma32(K,Q)) -> softmax lane-local. PV as mfma32(vT,P).
// exp2-domain softmax + defer-max (THR=8). Heavy bands first, XCD-grouped heads.
__global__ __launch_bounds__(256) void attn_k(
    const __bf16* __restrict__ qg, const __bf16* __restrict__ kg,
    const __bf16* __restrict__ vtg, const int* __restrict__ mflag,
    const int* __restrict__ mask, __bf16* __restrict__ ao)
{
    const int t = threadIdx.x;
    const int w = t >> 6, lane = t & 63;
    const int h = lane >> 5, l31 = lane & 31;
    // block -> (head-group, band): XCD x owns head-groups [4x,4x+4); heavy bands first
    const int xcd = blockIdx.x & 7;
    const int idx = blockIdx.x >> 3;          // 0..63
    const int hg  = xcd * 4 + (idx & 3);      // 0..31
    const int qb  = 15 - (idx >> 2);          // 128-query band, heavy first
    const int bI = hg >> 4, hI = hg & 15;
    const int q0w = (qb << 7) + (w << 5);
    const int iq = q0w + l31;
    const int diag = q0w >> 6;                // last 64-key tile (== mask row-tile)
    const size_t hoff = (size_t)hg * (2048 * 64);
    const __bf16* qh = qg + hoff;
    const __bf16* kh = kg + hoff;
    const __bf16* vh = vtg + hoff;

    bf16x8 qf[4];
#pragma unroll
    for (int i = 0; i < 4; ++i)
        qf[i] = *reinterpret_cast<const bf16x8*>(&qh[(size_t)iq * 64 + i * 16 + h * 8]);

    f32x16 o0 = {}, o1 = {};
    float mrun = -1e30f, lrun = 0.0f;

    for (int kt = 0; kt <= diag; ++kt) {
        const __bf16* kb = kh + ((size_t)kt << 12);       // K tile [64 keys][64 d]
        const __bf16* vb = vh + ((size_t)kt << 6);        // vT cols [64 d][64 keys]
        // K fragments + V fragments (V issued early; consumed after softmax)
        bf16x8 kf0[4], kf1[4], vf0[4], vf1[4];
#pragma unroll
        for (int i = 0; i < 4; ++i) {
            kf0[i] = *reinterpret_cast<const bf16x8*>(kb + l31 * 64 + i * 16 + h * 8);
            kf1[i] = *reinterpret_cast<const bf16x8*>(kb + (32 + l31) * 64 + i * 16 + h * 8);
            vf0[i] = *reinterpret_cast<const bf16x8*>(vb + (size_t)l31 * 2048 + i * 16 + h * 8);
            vf1[i] = *reinterpret_cast<const bf16x8*>(vb + (size_t)(32 + l31) * 2048 + i * 16 + h * 8);
        }
        // ---- S^T = K Q^T (exp2-domain scores; lane holds S[key][query=l31])
        f32x16 s0 = {}, s1 = {};
#pragma unroll
        for (int i = 0; i < 4; ++i) {
            s0 = MFMA32(kf0[i], qf[i], s0);
            s1 = MFMA32(kf1[i], qf[i], s1);
        }
        // ---- causal / padding mask (diag tile only; pad path never taken here)
        const bool pflag = (mflag[(bI * 32 + diag) * 32 + kt] == 0);
        if (pflag || kt == diag) {
            const int jb = kt * 64;
#pragma unroll
            for (int r = 0; r < 16; ++r) {
                const int cr = (r & 3) + 8 * (r >> 2) + 4 * h;
                const int j0 = jb + cr, j1 = jb + 32 + cr;
                float v0 = s0[r], v1 = s1[r];
                if (j0 > iq || (pflag && mask[((size_t)(bI * 2048 + iq)) * 2048 + j0] == 0)) v0 = -1e30f;
                if (j1 > iq || (pflag && mask[((size_t)(bI * 2048 + iq)) * 2048 + j1] == 0)) v1 = -1e30f;
                s0[r] = v0; s1[r] = v1;
            }
        }
        // ---- online softmax, exp2 domain, defer-max (THR=8)
        float mt = s0[0];
#pragma unroll
        for (int r = 1; r < 16; ++r) mt = fmaxf(mt, s0[r]);
#pragma unroll
        for (int r = 0; r < 16; ++r) mt = fmaxf(mt, s1[r]);
        mt = fmaxf(mt, __shfl_xor(mt, 32));
        if (!__all(mt <= mrun + 8.0f)) {
            const float mn = fmaxf(mrun, mt);
            const float alpha = exp2f(mrun - mn);
#pragma unroll
            for (int r = 0; r < 16; ++r) { o0[r] *= alpha; o1[r] *= alpha; }
            lrun *= alpha;
            mrun = mn;
        }
        float rs = 0.0f;
#pragma unroll
        for (int r = 0; r < 16; ++r) {
            const float p0 = exp2f(s0[r] - mrun); s0[r] = p0; rs += p0;
            const float p1 = exp2f(s1[r] - mrun); s1[r] = p1; rs += p1;
        }
        rs += __shfl_xor(rs, 32);
        lrun += rs;
        // ---- P redistribution to PV B-operand (pack + cross-half exchange)
        bf16x8 pa[4];
#pragma unroll
        for (int ks = 0; ks < 4; ++ks) {
            const int c0 = (ks & 1) * 8;
            unsigned A0, A1, B0, B1;
            if (ks < 2) {
                A0 = packbf(s0[c0 + 0], s0[c0 + 1]); A1 = packbf(s0[c0 + 2], s0[c0 + 3]);
                B0 = packbf(s0[c0 + 4], s0[c0 + 5]); B1 = packbf(s0[c0 + 6], s0[c0 + 7]);
            } else {
                A0 = packbf(s1[c0 + 0], s1[c0 + 1]); A1 = packbf(s1[c0 + 2], s1[c0 + 3]);
                B0 = packbf(s1[c0 + 4], s1[c0 + 5]); B1 = packbf(s1[c0 + 6], s1[c0 + 7]);
            }
            const unsigned Z0 = h ? A0 : B0;
            const unsigned Z1 = h ? A1 : B1;
            const unsigned X0 = (unsigned)__shfl_xor((int)Z0, 32);
            const unsigned X1 = (unsigned)__shfl_xor((int)Z1, 32);
            i32x4 wv;
            wv[0] = (int)(h ? X0 : A0);
            wv[1] = (int)(h ? X1 : A1);
            wv[2] = (int)(h ? B0 : X0);
            wv[3] = (int)(h ? B1 : X1);
            pa[ks] = __builtin_bit_cast(bf16x8, wv);
        }
        // ---- O += V^T P
#pragma unroll
        for (int ks = 0; ks < 4; ++ks) {
            o0 = MFMA32(vf0[ks], pa[ks], o0);
            o1 = MFMA32(vf1[ks], pa[ks], o1);
        }
    }

    // ---- epilogue: normalize, write ao[b][iq][hI*64 + d], d = 32db+8rq+4h+c
    const float inv = 1.0f / lrun;
    __bf16* aor = ao + ((size_t)(bI * 2048 + iq)) * 1024 + hI * 64 + h * 4;
#pragma unroll
    for (int rq = 0; rq < 4; ++rq) {
        bf16x4 st0, st1;
#pragma unroll
        for (int c2 = 0; c2 < 4; ++c2) {
            st0[c2] = (__bf16)(o0[rq * 4 + c2] * inv);
            st1[c2] = (__bf16)(o1[rq * 4 + c2] * inv);
        }
        *reinterpret_cast<bf16x4*>(&aor[rq * 8])      = st0;
        *reinterpret_cast<bf16x4*>(&aor[32 + rq * 8]) = st1;
    }
}

// ------------------------------- launch -----------------------------------------
extern "C" void kernel_launch(void* const* d_in, const int* in_sizes, int n_in,
                              void* d_out, int out_size, void* d_ws, size_t ws_size,
                              hipStream_t stream)
{
    const float* x      = (const float*)d_in[0];
    const int*   mask   = (const int*)d_in[1];
    const float* qkv_w  = (const float*)d_in[2];
    const float* qkv_b  = (const float*)d_in[3];
    const float* proj_w = (const float*)d_in[4];
    const float* proj_b = (const float*)d_in[5];
    float* out = (float*)d_out;

    char* ws = (char*)d_ws;
    __bf16* xb    = (__bf16*)(ws + 0);          // 4096x1024        8 MB
    __bf16* wqkv  = (__bf16*)(ws + 8388608);    // 3072x1024        6 MB
    __bf16* wproj = (__bf16*)(ws + 14680064);   // 1024x1024        2 MB
    __bf16* qg    = (__bf16*)(ws + 16777216);   // [32,2048,64]     8 MB
    __bf16* kg    = (__bf16*)(ws + 25165824);   // [32,2048,64]     8 MB
    __bf16* vtg   = (__bf16*)(ws + 33554432);   // [32,64,2048]     8 MB
    __bf16* ao    = (__bf16*)(ws + 41943040);   // 4096x1024        8 MB
    int*    mflag = (int*)(ws + 50331648);      // [2,32,32]        4 KB

    f32_to_bf16_k<<<1048576 / 256, 256, 0, stream>>>(x, xb, 1048576);
    f32_to_bf16_k<<<786432 / 256, 256, 0, stream>>>(qkv_w, wqkv, 786432);
    f32_to_bf16_k<<<262144 / 256, 256, 0, stream>>>(proj_w, wproj, 262144);
    mask_reduce_k<<<2 * 32 * 32, 256, 0, stream>>>(mask, mflag);
    gemm_qkv8_k<<<192, 512, 0, stream>>>(xb, wqkv, qkv_b, qg, kg, vtg);
    attn_k<<<512, 256, 0, stream>>>(qg, kg, vtg, mflag, mask, ao);
    gemm_proj_k<<<32 * 8, 256, 0, stream>>>(ao, wproj, proj_b, 4096, 1024, 1024, out);
}

// Round 5
// 173.938 us; speedup vs baseline: 1.0309x; 1.0309x over previous
//
#include <hip/hip_runtime.h>
#include <hip/hip_bf16.h>

// UnifiedAttention: x->QKV gemm -> causal MHA (H=16,D=64) -> proj gemm
// B=2, N=2048, C=1024. bf16 MFMA with fp32 accum throughout.

typedef __bf16 bf16x8 __attribute__((ext_vector_type(8)));
typedef __bf16 bf16x4 __attribute__((ext_vector_type(4)));
typedef __bf16 bf16x2 __attribute__((ext_vector_type(2)));
typedef float  f32x4  __attribute__((ext_vector_type(4)));
typedef float  f32x16 __attribute__((ext_vector_type(16)));
typedef int    i32x4  __attribute__((ext_vector_type(4)));

#define MFMA16(a, b, c) __builtin_amdgcn_mfma_f32_16x16x32_bf16((a), (b), (c), 0, 0, 0)
#define MFMA32(a, b, c) __builtin_amdgcn_mfma_f32_32x32x16_bf16((a), (b), (c), 0, 0, 0)

__device__ __forceinline__ void async_copy16(const __bf16* g, __bf16* l) {
    __builtin_amdgcn_global_load_lds(
        (const __attribute__((address_space(1))) void*)g,
        (__attribute__((address_space(3))) void*)l,
        16, 0, 0);
}

__device__ __forceinline__ unsigned packbf(float a, float b) {
    union { bf16x2 v; unsigned u; } un;
    un.v[0] = (__bf16)a; un.v[1] = (__bf16)b;
    return un.u;
}

// ---------------- fp32 -> bf16 conversion (vectorized) ----------------
__global__ void f32_to_bf16_k(const float* __restrict__ in, __bf16* __restrict__ out, int n4) {
    int i = blockIdx.x * blockDim.x + threadIdx.x;
    if (i >= n4) return;
    float4 v = reinterpret_cast<const float4*>(in)[i];
    bf16x4 o;
    o[0] = (__bf16)v.x; o[1] = (__bf16)v.y; o[2] = (__bf16)v.z; o[3] = (__bf16)v.w;
    reinterpret_cast<bf16x4*>(out)[i] = o;
}

// ---------------- mask tile reduction: 64x64 tiles -> all-ones flag ----------------
__global__ void mask_reduce_k(const int* __restrict__ mask, int* __restrict__ mflag) {
    __shared__ int ok;
    const int t = threadIdx.x;
    if (t == 0) ok = 1;
    __syncthreads();
    const int jt = blockIdx.x & 31;
    const int it = (blockIdx.x >> 5) & 31;
    const int b  = blockIdx.x >> 10;
    bool all1 = true;
#pragma unroll
    for (int c = 0; c < 4; ++c) {
        const int row = c * 16 + (t >> 4);
        const int col = (t & 15) * 4;
        const int4 v = *reinterpret_cast<const int4*>(
            &mask[((size_t)(b * 2048 + it * 64 + row)) * 2048 + jt * 64 + col]);
        all1 = all1 && v.x && v.y && v.z && v.w;
    }
    if (!all1) ok = 0;
    __syncthreads();
    if (t == 0) mflag[(b * 32 + it) * 32 + jt] = ok;
}

// ============ 8-phase 256x256 QKV GEMM (T1+T2+T3+T4+T5), K=1024 =================
#define BAR() asm volatile("s_barrier" ::: "memory")
#define VM2() asm volatile("s_waitcnt vmcnt(2)" ::: "memory")

__global__ __launch_bounds__(512, 2) void gemm_qkv8_k(
    const __bf16* __restrict__ A, const __bf16* __restrict__ Bm,
    const float* __restrict__ bias,
    __bf16* __restrict__ qg, __bf16* __restrict__ kg, __bf16* __restrict__ vtg)
{
    __shared__ __align__(16) __bf16 As[2][16384];   // [buf][256 rows x 64]
    __shared__ __align__(16) __bf16 Bs[2][16384];

    const int t = threadIdx.x;
    const int lane = t & 63;
    const int w = t >> 6;
    const int wr = w >> 2, wc = w & 3;
    const int li = lane & 15, g = lane >> 4;

    // XCD-aware bijective swizzle (grid=192, 192%8==0, 24 blocks per XCD)
    const int bid = (blockIdx.x & 7) * 24 + (blockIdx.x >> 3);
    const int m0 = (bid / 12) << 8;     // N tiles = 3072/256 = 12
    const int n0 = (bid % 12) << 8;

    const int srow = t >> 3;
    const int scol = ((t & 7) ^ (srow & 7)) << 3;
    const __bf16* pA = A  + (size_t)(m0 + srow) * 1024 + scol;
    const __bf16* pB = Bm + (size_t)(n0 + srow) * 1024 + scol;
    __bf16* dA = &As[0][0] + t * 8;
    __bf16* dB = &Bs[0][0] + t * 8;

#define STAGE_A(BB, T, HH) do {                                                   \
    const size_t ro_ = (size_t)((HH) * 128) * 1024 + (size_t)(T) * 64;            \
    async_copy16(pA + ro_,         dA + (BB) * 16384 + (HH) * 8192);              \
    async_copy16(pA + ro_ + 65536, dA + (BB) * 16384 + (HH) * 8192 + 4096);       \
  } while (0)
#define STAGE_B(BB, T, HH) do {                                                   \
    const size_t ro_ = (size_t)((HH) * 128) * 1024 + (size_t)(T) * 64;            \
    async_copy16(pB + ro_,         dB + (BB) * 16384 + (HH) * 8192);              \
    async_copy16(pB + ro_ + 65536, dB + (BB) * 16384 + (HH) * 8192 + 4096);       \
  } while (0)

    const int aoff0 = ((0 + g) ^ (li & 7)) << 3;
    const int aoff1 = ((4 + g) ^ (li & 7)) << 3;
    const int abase = (wr * 128 + li) * 64;
    const int bbase = (wc * 64 + li) * 64;

    f32x4 acc[8][4] = {};
    bf16x8 a[4][2], b[2][2][2];

#define READ_A(BB, MH) do { _Pragma("unroll")                                     \
    for (int mi2 = 0; mi2 < 4; ++mi2) {                                           \
      const __bf16* p_ = &As[BB][abase + ((MH) * 4 + mi2) * 1024];                \
      a[mi2][0] = *reinterpret_cast<const bf16x8*>(p_ + aoff0);                   \
      a[mi2][1] = *reinterpret_cast<const bf16x8*>(p_ + aoff1); } } while (0)
#define READ_B(BB, NH) do { _Pragma("unroll")                                     \
    for (int ni2 = 0; ni2 < 2; ++ni2) {                                           \
      const __bf16* p_ = &Bs[BB][bbase + ((NH) * 2 + ni2) * 1024];                \
      b[NH][ni2][0] = *reinterpret_cast<const bf16x8*>(p_ + aoff0);               \
      b[NH][ni2][1] = *reinterpret_cast<const bf16x8*>(p_ + aoff1); } } while (0)
#define MFMA_QUAD(MH, NH) do {                                                    \
    __builtin_amdgcn_s_setprio(1);                                                \
    _Pragma("unroll") for (int mi2 = 0; mi2 < 4; ++mi2)                           \
    _Pragma("unroll") for (int ni2 = 0; ni2 < 2; ++ni2) {                         \
      f32x4 c_ = acc[(MH) * 4 + mi2][(NH) * 2 + ni2];                             \
      c_ = MFMA16(a[mi2][0], b[NH][ni2][0], c_);                                  \
      c_ = MFMA16(a[mi2][1], b[NH][ni2][1], c_);                                  \
      acc[(MH) * 4 + mi2][(NH) * 2 + ni2] = c_; }                                 \
    __builtin_amdgcn_s_setprio(0); } while (0)

#define KTILE(BB, T) do {                                                         \
    const int Tn_  = ((T) + 1 < 16) ? (T) + 1 : 15;                               \
    const int Tn2_ = ((T) + 2 < 16) ? (T) + 2 : 15;                               \
    STAGE_A((BB) ^ 1, Tn_, 1);                                                    \
    READ_A(BB, 0); READ_B(BB, 0);                                                 \
    BAR(); MFMA_QUAD(0, 0); BAR();                                                \
    STAGE_B((BB) ^ 1, Tn_, 0);                                                    \
    READ_B(BB, 1);                                                                \
    BAR(); MFMA_QUAD(0, 1); BAR();                                                \
    STAGE_B((BB) ^ 1, Tn_, 1);                                                    \
    READ_A(BB, 1);                                                                \
    BAR(); MFMA_QUAD(1, 0); BAR();                                                \
    STAGE_A((BB), Tn2_, 0);                                                       \
    VM2(); BAR(); MFMA_QUAD(1, 1); BAR();                                         \
  } while (0)

    STAGE_A(0, 0, 0); STAGE_A(0, 0, 1);
    STAGE_B(0, 0, 0); STAGE_B(0, 0, 1);
    STAGE_A(1, 1, 0);
    VM2(); BAR();

#pragma unroll 1
    for (int jj = 0; jj < 8; ++jj) {
        KTILE(0, 2 * jj);
        KTILE(1, 2 * jj + 1);
    }

    // ---- epilogue: scatter into q (scaled by 0.125*log2e for exp2 softmax) / k / vT
    const int nbase = n0 + wc * 64;
    const int s = nbase >> 10;
    const int headg = (m0 >> 11) * 16 + ((nbase & 1023) >> 6);
    const int mrow = (m0 & 2047) + wr * 128 + g * 4;
    float bv[4];
#pragma unroll
    for (int ni = 0; ni < 4; ++ni) bv[ni] = bias[nbase + ni * 16 + li];

    if (s == 2) {
#pragma unroll
        for (int mi = 0; mi < 8; ++mi) {
#pragma unroll
            for (int ni = 0; ni < 4; ++ni) {
                bf16x4 st;
#pragma unroll
                for (int r = 0; r < 4; ++r) st[r] = (__bf16)(acc[mi][ni][r] + bv[ni]);
                *reinterpret_cast<bf16x4*>(
                    &vtg[((size_t)(headg * 64) + ni * 16 + li) * 2048 + mrow + mi * 16]) = st;
            }
        }
    } else {
        __bf16* og = (s == 0) ? qg : kg;
        const float sc = (s == 0) ? 0.18033688f : 1.0f;   // 0.125 * log2(e)
#pragma unroll
        for (int mi = 0; mi < 8; ++mi) {
#pragma unroll
            for (int r = 0; r < 4; ++r) {
                __bf16* rp = og + ((size_t)headg * 2048 + mrow + mi * 16 + r) * 64;
#pragma unroll
                for (int ni = 0; ni < 4; ++ni)
                    rp[ni * 16 + li] = (__bf16)((acc[mi][ni][r] + bv[ni]) * sc);
            }
        }
    }
#undef KTILE
#undef MFMA_QUAD
#undef READ_A
#undef READ_B
#undef STAGE_A
#undef STAGE_B
}

// ---------------- 2-phase 128x128 GEMM (proj): C = A*Bm^T + bias, fp32 out -------
__global__ __launch_bounds__(256) void gemm_proj_k(
    const __bf16* __restrict__ A, const __bf16* __restrict__ Bm,
    const float* __restrict__ bias, int M, int N, int K,
    float* __restrict__ outf)
{
    __shared__ __align__(16) __bf16 As[128 * 64];
    __shared__ __align__(16) __bf16 Bs[128 * 64];
    const int t = threadIdx.x;
    const int nb = N >> 7;
    const int m0 = (blockIdx.x / nb) << 7;
    const int n0 = (blockIdx.x % nb) << 7;
    const int lane = t & 63, w = t >> 6;
    const int g = lane >> 4, li = lane & 15;
    const int wr = w >> 1, wc = w & 1;
    const __bf16* Ab = A + (size_t)m0 * K;
    const __bf16* Bb = Bm + (size_t)n0 * K;

    f32x4 acc[4][4] = {};

    for (int k0 = 0; k0 < K; k0 += 64) {
#pragma unroll
        for (int c = 0; c < 4; ++c) {
            const int e = (c * 256 + t) * 8;
            const int row = e >> 6;
            const int col = e & 63;
            async_copy16(Ab + (size_t)row * K + k0 + col, As + e);
            async_copy16(Bb + (size_t)row * K + k0 + col, Bs + e);
        }
        __syncthreads();
#pragma unroll
        for (int kk = 0; kk < 2; ++kk) {
            bf16x8 af[4], bf[4];
#pragma unroll
            for (int mi = 0; mi < 4; ++mi)
                af[mi] = *reinterpret_cast<const bf16x8*>(
                    &As[(wr * 64 + mi * 16 + li) * 64 + kk * 32 + g * 8]);
#pragma unroll
            for (int ni = 0; ni < 4; ++ni)
                bf[ni] = *reinterpret_cast<const bf16x8*>(
                    &Bs[(wc * 64 + ni * 16 + li) * 64 + kk * 32 + g * 8]);
#pragma unroll
            for (int mi = 0; mi < 4; ++mi)
#pragma unroll
                for (int ni = 0; ni < 4; ++ni)
                    acc[mi][ni] = MFMA16(af[mi], bf[ni], acc[mi][ni]);
        }
        __syncthreads();
    }

#pragma unroll
    for (int mi = 0; mi < 4; ++mi) {
#pragma unroll
        for (int ni = 0; ni < 4; ++ni) {
            const int n = n0 + wc * 64 + ni * 16 + li;
            const float bv = bias[n];
#pragma unroll
            for (int r = 0; r < 4; ++r) {
                const int m = m0 + wr * 64 + mi * 16 + g * 4 + r;
                outf[(size_t)m * N + n] = acc[mi][ni][r] + bv;
            }
        }
    }
}

// ------- flash attention, causal: barrier-free, per-wave-private LDS staging ------
// q:[BH,2048,64] (scale*log2e prefolded), k:[BH,2048,64], vT:[BH,64,2048] bf16.
// 4 independent waves x 32 queries per block; each wave owns 16KB LDS and
// double-buffers its own 32-key K/V tile via global_load_lds (coalesced),
// synced only by its own counted vmcnt(8). No __syncthreads anywhere.
// Swapped QK^T (mfma32(K,Q)) -> softmax lane-local, exp2-domain, defer-max.
__global__ __launch_bounds__(256) void attn_k(
    const __bf16* __restrict__ qg, const __bf16* __restrict__ kg,
    const __bf16* __restrict__ vtg, const int* __restrict__ mflag,
    const int* __restrict__ mask, __bf16* __restrict__ ao)
{
    __shared__ __align__(16) __bf16 lds[4][8192];   // 64KB: 16KB per wave
    const int t = threadIdx.x;
    const int w = t >> 6, lane = t & 63;
    const int h = lane >> 5, l31 = lane & 31;
    // block -> (head-group, band): XCD x owns head-groups [4x,4x+4); heavy first
    const int xcd = blockIdx.x & 7;
    const int idx = blockIdx.x >> 3;          // 0..63
    const int hg  = xcd * 4 + (idx & 3);      // 0..31
    const int qb  = 15 - (idx >> 2);          // 128-query band, heavy first
    const int bI = hg >> 4, hI = hg & 15;
    const int q0w = (qb << 7) + (w << 5);     // this wave's 32 queries
    const int iq = q0w + l31;
    const int diag = q0w >> 5;                // last 32-key tile index
    const int rowt = q0w >> 6;                // 64-row mask tile
    const size_t hoff = (size_t)hg * (2048 * 64);
    const __bf16* qh = qg + hoff;
    const __bf16* kh = kg + hoff;
    const __bf16* vh = vtg + hoff;
    char* myb = (char*)&lds[w][0];            // K[buf]: +buf*4096; V[buf]: +8192+buf*4096

    bf16x8 qf[4];
#pragma unroll
    for (int i = 0; i < 4; ++i)
        qf[i] = *reinterpret_cast<const bf16x8*>(&qh[(size_t)iq * 64 + i * 16 + h * 8]);

    f32x16 o0 = {}, o1 = {};
    float mrun = -1e30f, lrun = 0.0f;

    // per-wave stage of one 32-key tile: K 4KB (32r x 128B) + V 4KB (64r x 64B)
#define STAGE(BUF, KT) do {                                                       \
    _Pragma("unroll")                                                             \
    for (int i_ = 0; i_ < 4; ++i_) {                                              \
        const int p_ = i_ * 1024 + lane * 16;                                     \
        const int kr_ = p_ >> 7, ksl_ = (p_ >> 4) & 7;                            \
        async_copy16(kh + (size_t)(((KT) << 5) + kr_) * 64 + ((ksl_ ^ (kr_ & 7)) << 3), \
                     (__bf16*)(myb + (BUF) * 4096 + p_));                         \
        const int vr_ = p_ >> 6, vsl_ = (p_ >> 4) & 3;                            \
        async_copy16(vh + (size_t)vr_ * 2048 + ((KT) << 5) + ((vsl_ ^ (vr_ & 3)) << 3), \
                     (__bf16*)(myb + 8192 + (BUF) * 4096 + p_));                  \
    }                                                                             \
} while (0)

    int cur = 0;
    __builtin_amdgcn_sched_barrier(0);
    STAGE(0, 0);
    for (int kt = 0; kt <= diag; ++kt) {
        __builtin_amdgcn_sched_barrier(0);
        if (kt < diag) {
            STAGE(cur ^ 1, kt + 1);
            asm volatile("s_waitcnt vmcnt(8)" ::: "memory");   // prev 8 stage loads done
        } else {
            asm volatile("s_waitcnt vmcnt(0)" ::: "memory");
        }
        __builtin_amdgcn_sched_barrier(0);
        const char* kb = myb + cur * 4096;
        const char* vb = myb + 8192 + cur * 4096;
        // ---- S^T = K Q^T (32 keys x 32 queries), K from swizzled LDS
        bf16x8 kf[4];
#pragma unroll
        for (int i = 0; i < 4; ++i)
            kf[i] = *reinterpret_cast<const bf16x8*>(
                kb + l31 * 128 + (((i * 2 + h) ^ (l31 & 7)) << 4));
        f32x16 s0 = {};
        __builtin_amdgcn_s_setprio(1);
#pragma unroll
        for (int i = 0; i < 4; ++i) s0 = MFMA32(kf[i], qf[i], s0);
        __builtin_amdgcn_s_setprio(0);
        // ---- causal / padding mask (diag tile only; pad path never taken here)
        const bool pflag = (mflag[(bI * 32 + rowt) * 32 + (kt >> 1)] == 0);
        if (pflag || kt == diag) {
            const int jb = kt * 32;
#pragma unroll
            for (int r = 0; r < 16; ++r) {
                const int j0 = jb + (r & 3) + 8 * (r >> 2) + 4 * h;
                float v0 = s0[r];
                if (j0 > iq || (pflag && mask[((size_t)(bI * 2048 + iq)) * 2048 + j0] == 0))
                    v0 = -1e30f;
                s0[r] = v0;
            }
        }
        // ---- online softmax, exp2 domain, defer-max (THR=8)
        float mt = s0[0];
#pragma unroll
        for (int r = 1; r < 16; ++r) mt = fmaxf(mt, s0[r]);
        mt = fmaxf(mt, __shfl_xor(mt, 32));
        if (!__all(mt <= mrun + 8.0f)) {
            const float mn = fmaxf(mrun, mt);
            const float alpha = exp2f(mrun - mn);
#pragma unroll
            for (int r = 0; r < 16; ++r) { o0[r] *= alpha; o1[r] *= alpha; }
            lrun *= alpha;
            mrun = mn;
        }
        float rs = 0.0f;
#pragma unroll
        for (int r = 0; r < 16; ++r) {
            const float p0 = exp2f(s0[r] - mrun); s0[r] = p0; rs += p0;
        }
        rs += __shfl_xor(rs, 32);
        lrun += rs;
        // ---- P redistribution to PV B-operand (pack + cross-half exchange)
        bf16x8 pa[2];
#pragma unroll
        for (int ks = 0; ks < 2; ++ks) {
            const int c0 = ks * 8;
            unsigned A0 = packbf(s0[c0 + 0], s0[c0 + 1]), A1 = packbf(s0[c0 + 2], s0[c0 + 3]);
            unsigned B0 = packbf(s0[c0 + 4], s0[c0 + 5]), B1 = packbf(s0[c0 + 6], s0[c0 + 7]);
            const unsigned Z0 = h ? A0 : B0, Z1 = h ? A1 : B1;
            const unsigned X0 = (unsigned)__shfl_xor((int)Z0, 32);
            const unsigned X1 = (unsigned)__shfl_xor((int)Z1, 32);
            i32x4 wv;
            wv[0] = (int)(h ? X0 : A0); wv[1] = (int)(h ? X1 : A1);
            wv[2] = (int)(h ? B0 : X0); wv[3] = (int)(h ? B1 : X1);
            pa[ks] = __builtin_bit_cast(bf16x8, wv);
        }
        // ---- O += V^T P, V from swizzled LDS (rows d, 4 slots of 16B)
#pragma unroll
        for (int ks = 0; ks < 2; ++ks) {
            const int off = ((ks * 2 + h) ^ (l31 & 3)) << 4;
            bf16x8 v0 = *reinterpret_cast<const bf16x8*>(vb + l31 * 64 + off);
            bf16x8 v1 = *reinterpret_cast<const bf16x8*>(vb + (32 + l31) * 64 + off);
            __builtin_amdgcn_s_setprio(1);
            o0 = MFMA32(v0, pa[ks], o0);
            o1 = MFMA32(v1, pa[ks], o1);
            __builtin_amdgcn_s_setprio(0);
        }
        cur ^= 1;
    }
#undef STAGE

    // ---- epilogue: normalize, write ao[b][iq][hI*64 + d], d = 8rq + 4h + c (+32)
    const float inv = 1.0f / lrun;
    __bf16* aor = ao + ((size_t)(bI * 2048 + iq)) * 1024 + hI * 64 + h * 4;
#pragma unroll
    for (int rq = 0; rq < 4; ++rq) {
        bf16x4 st0, st1;
#pragma unroll
        for (int c2 = 0; c2 < 4; ++c2) {
            st0[c2] = (__bf16)(o0[rq * 4 + c2] * inv);
            st1[c2] = (__bf16)(o1[rq * 4 + c2] * inv);
        }
        *reinterpret_cast<bf16x4*>(&aor[rq * 8])      = st0;
        *reinterpret_cast<bf16x4*>(&aor[32 + rq * 8]) = st1;
    }
}

// ------------------------------- launch -----------------------------------------
extern "C" void kernel_launch(void* const* d_in, const int* in_sizes, int n_in,
                              void* d_out, int out_size, void* d_ws, size_t ws_size,
                              hipStream_t stream)
{
    const float* x      = (const float*)d_in[0];
    const int*   mask   = (const int*)d_in[1];
    const float* qkv_w  = (const float*)d_in[2];
    const float* qkv_b  = (const float*)d_in[3];
    const float* proj_w = (const float*)d_in[4];
    const float* proj_b = (const float*)d_in[5];
    float* out = (float*)d_out;

    char* ws = (char*)d_ws;
    __bf16* xb    = (__bf16*)(ws + 0);          // 4096x1024        8 MB
    __bf16* wqkv  = (__bf16*)(ws + 8388608);    // 3072x1024        6 MB
    __bf16* wproj = (__bf16*)(ws + 14680064);   // 1024x1024        2 MB
    __bf16* qg    = (__bf16*)(ws + 16777216);   // [32,2048,64]     8 MB
    __bf16* kg    = (__bf16*)(ws + 25165824);   // [32,2048,64]     8 MB
    __bf16* vtg   = (__bf16*)(ws + 33554432);   // [32,64,2048]     8 MB
    __bf16* ao    = (__bf16*)(ws + 41943040);   // 4096x1024        8 MB
    int*    mflag = (int*)(ws + 50331648);      // [2,32,32]        4 KB

    f32_to_bf16_k<<<1048576 / 256, 256, 0, stream>>>(x, xb, 1048576);
    f32_to_bf16_k<<<786432 / 256, 256, 0, stream>>>(qkv_w, wqkv, 786432);
    f32_to_bf16_k<<<262144 / 256, 256, 0, stream>>>(proj_w, wproj, 262144);
    mask_reduce_k<<<2 * 32 * 32, 256, 0, stream>>>(mask, mflag);
    gemm_qkv8_k<<<192, 512, 0, stream>>>(xb, wqkv, qkv_b, qg, kg, vtg);
    attn_k<<<512, 256, 0, stream>>>(qg, kg, vtg, mflag, mask, ao);
    gemm_proj_k<<<32 * 8, 256, 0, stream>>>(ao, wproj, proj_b, 4096, 1024, 1024, out);
}

// Round 6
// 138.171 us; speedup vs baseline: 1.2978x; 1.2589x over previous
//
#include <hip/hip_runtime.h>
#include <hip/hip_bf16.h>

// UnifiedAttention: x->QKV gemm -> causal MHA (H=16,D=64) -> proj gemm
// B=2, N=2048, C=1024. bf16 MFMA with fp32 accum throughout.

typedef __bf16 bf16x8 __attribute__((ext_vector_type(8)));
typedef __bf16 bf16x4 __attribute__((ext_vector_type(4)));
typedef __bf16 bf16x2 __attribute__((ext_vector_type(2)));
typedef float  f32x4  __attribute__((ext_vector_type(4)));
typedef float  f32x16 __attribute__((ext_vector_type(16)));
typedef int    i32x4  __attribute__((ext_vector_type(4)));

#define MFMA16(a, b, c) __builtin_amdgcn_mfma_f32_16x16x32_bf16((a), (b), (c), 0, 0, 0)

__device__ __forceinline__ void async_copy16(const __bf16* g, __bf16* l) {
    __builtin_amdgcn_global_load_lds(
        (const __attribute__((address_space(1))) void*)g,
        (__attribute__((address_space(3))) void*)l,
        16, 0, 0);
}

__device__ __forceinline__ unsigned packbf(float a, float b) {
    union { bf16x2 v; unsigned u; } un;
    un.v[0] = (__bf16)a; un.v[1] = (__bf16)b;
    return un.u;
}

// ---------------- fp32 -> bf16 conversion (vectorized) ----------------
__global__ void f32_to_bf16_k(const float* __restrict__ in, __bf16* __restrict__ out, int n4) {
    int i = blockIdx.x * blockDim.x + threadIdx.x;
    if (i >= n4) return;
    float4 v = reinterpret_cast<const float4*>(in)[i];
    bf16x4 o;
    o[0] = (__bf16)v.x; o[1] = (__bf16)v.y; o[2] = (__bf16)v.z; o[3] = (__bf16)v.w;
    reinterpret_cast<bf16x4*>(out)[i] = o;
}

// ---------------- mask tile reduction: 64x64 tiles -> all-ones flag ----------------
__global__ void mask_reduce_k(const int* __restrict__ mask, int* __restrict__ mflag) {
    __shared__ int ok;
    const int t = threadIdx.x;
    if (t == 0) ok = 1;
    __syncthreads();
    const int jt = blockIdx.x & 31;
    const int it = (blockIdx.x >> 5) & 31;
    const int b  = blockIdx.x >> 10;
    bool all1 = true;
#pragma unroll
    for (int c = 0; c < 4; ++c) {
        const int row = c * 16 + (t >> 4);
        const int col = (t & 15) * 4;
        const int4 v = *reinterpret_cast<const int4*>(
            &mask[((size_t)(b * 2048 + it * 64 + row)) * 2048 + jt * 64 + col]);
        all1 = all1 && v.x && v.y && v.z && v.w;
    }
    if (!all1) ok = 0;
    __syncthreads();
    if (t == 0) mflag[(b * 32 + it) * 32 + jt] = ok;
}

// ============ 8-phase 256x256 QKV GEMM (T1+T2+T3+T4+T5), K=1024 =================
#define BAR() asm volatile("s_barrier" ::: "memory")
#define VM2() asm volatile("s_waitcnt vmcnt(2)" ::: "memory")

__global__ __launch_bounds__(512, 2) void gemm_qkv8_k(
    const __bf16* __restrict__ A, const __bf16* __restrict__ Bm,
    const float* __restrict__ bias,
    __bf16* __restrict__ qg, __bf16* __restrict__ kg, __bf16* __restrict__ vtg)
{
    __shared__ __align__(16) __bf16 As[2][16384];   // [buf][256 rows x 64]
    __shared__ __align__(16) __bf16 Bs[2][16384];

    const int t = threadIdx.x;
    const int lane = t & 63;
    const int w = t >> 6;
    const int wr = w >> 2, wc = w & 3;
    const int li = lane & 15, g = lane >> 4;

    // XCD-aware bijective swizzle (grid=192, 192%8==0, 24 blocks per XCD)
    const int bid = (blockIdx.x & 7) * 24 + (blockIdx.x >> 3);
    const int m0 = (bid / 12) << 8;     // N tiles = 3072/256 = 12
    const int n0 = (bid % 12) << 8;

    const int srow = t >> 3;
    const int scol = ((t & 7) ^ (srow & 7)) << 3;
    const __bf16* pA = A  + (size_t)(m0 + srow) * 1024 + scol;
    const __bf16* pB = Bm + (size_t)(n0 + srow) * 1024 + scol;
    __bf16* dA = &As[0][0] + t * 8;
    __bf16* dB = &Bs[0][0] + t * 8;

#define STAGE_A(BB, T, HH) do {                                                   \
    const size_t ro_ = (size_t)((HH) * 128) * 1024 + (size_t)(T) * 64;            \
    async_copy16(pA + ro_,         dA + (BB) * 16384 + (HH) * 8192);              \
    async_copy16(pA + ro_ + 65536, dA + (BB) * 16384 + (HH) * 8192 + 4096);       \
  } while (0)
#define STAGE_B(BB, T, HH) do {                                                   \
    const size_t ro_ = (size_t)((HH) * 128) * 1024 + (size_t)(T) * 64;            \
    async_copy16(pB + ro_,         dB + (BB) * 16384 + (HH) * 8192);              \
    async_copy16(pB + ro_ + 65536, dB + (BB) * 16384 + (HH) * 8192 + 4096);       \
  } while (0)

    const int aoff0 = ((0 + g) ^ (li & 7)) << 3;
    const int aoff1 = ((4 + g) ^ (li & 7)) << 3;
    const int abase = (wr * 128 + li) * 64;
    const int bbase = (wc * 64 + li) * 64;

    f32x4 acc[8][4] = {};
    bf16x8 a[4][2], b[2][2][2];

#define READ_A(BB, MH) do { _Pragma("unroll")                                     \
    for (int mi2 = 0; mi2 < 4; ++mi2) {                                           \
      const __bf16* p_ = &As[BB][abase + ((MH) * 4 + mi2) * 1024];                \
      a[mi2][0] = *reinterpret_cast<const bf16x8*>(p_ + aoff0);                   \
      a[mi2][1] = *reinterpret_cast<const bf16x8*>(p_ + aoff1); } } while (0)
#define READ_B(BB, NH) do { _Pragma("unroll")                                     \
    for (int ni2 = 0; ni2 < 2; ++ni2) {                                           \
      const __bf16* p_ = &Bs[BB][bbase + ((NH) * 2 + ni2) * 1024];                \
      b[NH][ni2][0] = *reinterpret_cast<const bf16x8*>(p_ + aoff0);               \
      b[NH][ni2][1] = *reinterpret_cast<const bf16x8*>(p_ + aoff1); } } while (0)
#define MFMA_QUAD(MH, NH) do {                                                    \
    __builtin_amdgcn_s_setprio(1);                                                \
    _Pragma("unroll") for (int mi2 = 0; mi2 < 4; ++mi2)                           \
    _Pragma("unroll") for (int ni2 = 0; ni2 < 2; ++ni2) {                         \
      f32x4 c_ = acc[(MH) * 4 + mi2][(NH) * 2 + ni2];                             \
      c_ = MFMA16(a[mi2][0], b[NH][ni2][0], c_);                                  \
      c_ = MFMA16(a[mi2][1], b[NH][ni2][1], c_);                                  \
      acc[(MH) * 4 + mi2][(NH) * 2 + ni2] = c_; }                                 \
    __builtin_amdgcn_s_setprio(0); } while (0)

#define KTILE(BB, T) do {                                                         \
    const int Tn_  = ((T) + 1 < 16) ? (T) + 1 : 15;                               \
    const int Tn2_ = ((T) + 2 < 16) ? (T) + 2 : 15;                               \
    STAGE_A((BB) ^ 1, Tn_, 1);                                                    \
    READ_A(BB, 0); READ_B(BB, 0);                                                 \
    BAR(); MFMA_QUAD(0, 0); BAR();                                                \
    STAGE_B((BB) ^ 1, Tn_, 0);                                                    \
    READ_B(BB, 1);                                                                \
    BAR(); MFMA_QUAD(0, 1); BAR();                                                \
    STAGE_B((BB) ^ 1, Tn_, 1);                                                    \
    READ_A(BB, 1);                                                                \
    BAR(); MFMA_QUAD(1, 0); BAR();                                                \
    STAGE_A((BB), Tn2_, 0);                                                       \
    VM2(); BAR(); MFMA_QUAD(1, 1); BAR();                                         \
  } while (0)

    STAGE_A(0, 0, 0); STAGE_A(0, 0, 1);
    STAGE_B(0, 0, 0); STAGE_B(0, 0, 1);
    STAGE_A(1, 1, 0);
    VM2(); BAR();

#pragma unroll 1
    for (int jj = 0; jj < 8; ++jj) {
        KTILE(0, 2 * jj);
        KTILE(1, 2 * jj + 1);
    }

    // ---- epilogue: scatter into q (scaled by 0.125*log2e for exp2 softmax) / k / vT
    const int nbase = n0 + wc * 64;
    const int s = nbase >> 10;
    const int headg = (m0 >> 11) * 16 + ((nbase & 1023) >> 6);
    const int mrow = (m0 & 2047) + wr * 128 + g * 4;
    float bv[4];
#pragma unroll
    for (int ni = 0; ni < 4; ++ni) bv[ni] = bias[nbase + ni * 16 + li];

    if (s == 2) {
#pragma unroll
        for (int mi = 0; mi < 8; ++mi) {
#pragma unroll
            for (int ni = 0; ni < 4; ++ni) {
                bf16x4 st;
#pragma unroll
                for (int r = 0; r < 4; ++r) st[r] = (__bf16)(acc[mi][ni][r] + bv[ni]);
                *reinterpret_cast<bf16x4*>(
                    &vtg[((size_t)(headg * 64) + ni * 16 + li) * 2048 + mrow + mi * 16]) = st;
            }
        }
    } else {
        __bf16* og = (s == 0) ? qg : kg;
        const float sc = (s == 0) ? 0.18033688f : 1.0f;   // 0.125 * log2(e)
#pragma unroll
        for (int mi = 0; mi < 8; ++mi) {
#pragma unroll
            for (int r = 0; r < 4; ++r) {
                __bf16* rp = og + ((size_t)headg * 2048 + mrow + mi * 16 + r) * 64;
#pragma unroll
                for (int ni = 0; ni < 4; ++ni)
                    rp[ni * 16 + li] = (__bf16)((acc[mi][ni][r] + bv[ni]) * sc);
            }
        }
    }
#undef KTILE
#undef MFMA_QUAD
#undef READ_A
#undef READ_B
#undef STAGE_A
#undef STAGE_B
}

// ---------------- 2-phase 128x128 GEMM (proj): C = A*Bm^T + bias, fp32 out -------
__global__ __launch_bounds__(256) void gemm_proj_k(
    const __bf16* __restrict__ A, const __bf16* __restrict__ Bm,
    const float* __restrict__ bias, int M, int N, int K,
    float* __restrict__ outf)
{
    __shared__ __align__(16) __bf16 As[128 * 64];
    __shared__ __align__(16) __bf16 Bs[128 * 64];
    const int t = threadIdx.x;
    const int nb = N >> 7;
    const int m0 = (blockIdx.x / nb) << 7;
    const int n0 = (blockIdx.x % nb) << 7;
    const int lane = t & 63, w = t >> 6;
    const int g = lane >> 4, li = lane & 15;
    const int wr = w >> 1, wc = w & 1;
    const __bf16* Ab = A + (size_t)m0 * K;
    const __bf16* Bb = Bm + (size_t)n0 * K;

    f32x4 acc[4][4] = {};

    for (int k0 = 0; k0 < K; k0 += 64) {
#pragma unroll
        for (int c = 0; c < 4; ++c) {
            const int e = (c * 256 + t) * 8;
            const int row = e >> 6;
            const int col = e & 63;
            async_copy16(Ab + (size_t)row * K + k0 + col, As + e);
            async_copy16(Bb + (size_t)row * K + k0 + col, Bs + e);
        }
        __syncthreads();
#pragma unroll
        for (int kk = 0; kk < 2; ++kk) {
            bf16x8 af[4], bf[4];
#pragma unroll
            for (int mi = 0; mi < 4; ++mi)
                af[mi] = *reinterpret_cast<const bf16x8*>(
                    &As[(wr * 64 + mi * 16 + li) * 64 + kk * 32 + g * 8]);
#pragma unroll
            for (int ni = 0; ni < 4; ++ni)
                bf[ni] = *reinterpret_cast<const bf16x8*>(
                    &Bs[(wc * 64 + ni * 16 + li) * 64 + kk * 32 + g * 8]);
#pragma unroll
            for (int mi = 0; mi < 4; ++mi)
#pragma unroll
                for (int ni = 0; ni < 4; ++ni)
                    acc[mi][ni] = MFMA16(af[mi], bf[ni], acc[mi][ni]);
        }
        __syncthreads();
    }

#pragma unroll
    for (int mi = 0; mi < 4; ++mi) {
#pragma unroll
        for (int ni = 0; ni < 4; ++ni) {
            const int n = n0 + wc * 64 + ni * 16 + li;
            const float bv = bias[n];
#pragma unroll
            for (int r = 0; r < 4; ++r) {
                const int m = m0 + wr * 64 + mi * 16 + g * 4 + r;
                outf[(size_t)m * N + n] = acc[mi][ni][r] + bv;
            }
        }
    }
}

// ------- flash attention, causal: 16q/wave MFMA16, shared 64-key staging ---------
// q:[BH,2048,64] (scale*log2e prefolded), k:[BH,2048,64], vT:[BH,64,2048] bf16.
// 1024 blocks = (head, 64q band); 4 waves x 16 queries. All waves share one
// staged K/V tile (dbuf, one __syncthreads per tile); same diag for all waves.
// Swapped QK^T (mfma16(K,Q)) -> softmax lane-local (16 scores) + 2 shfl.
// P goes through per-wave swizzled LDS (4x ds_write_b64 -> 2x ds_read_b128)
// directly into the PV B-operand layout. exp2-domain + defer-max (THR=8).
__global__ __launch_bounds__(256) void attn_k(
    const __bf16* __restrict__ qg, const __bf16* __restrict__ kg,
    const __bf16* __restrict__ vtg, const int* __restrict__ mflag,
    const int* __restrict__ mask, __bf16* __restrict__ ao)
{
    __shared__ __align__(16) __bf16 Ks[2][4096];   // [64 keys][64 d], 16B-slot XOR-swz
    __shared__ __align__(16) __bf16 Vs[2][4096];   // [64 d][64 keys], XOR-swz
    __shared__ __align__(16) __bf16 Ps[4][1024];   // per-wave P [16 q][64 keys], XOR-swz
    const int t = threadIdx.x;
    const int w = t >> 6, lane = t & 63;
    const int li = lane & 15, g = lane >> 4;
    // block -> (head-group, band): XCD x owns head-groups [4x,4x+4); heavy first
    const int xcd = blockIdx.x & 7;
    const int idx = blockIdx.x >> 3;          // 0..127
    const int hg  = xcd * 4 + (idx & 3);      // 0..31
    const int band = 31 - (idx >> 2);         // 64-query band, heavy first
    const int bI = hg >> 4, hI = hg & 15;
    const int iq = band * 64 + w * 16 + li;   // this lane's query row
    const int diag = band;                    // last 64-key tile (== mask row-tile)
    const size_t hoff = (size_t)hg * (2048 * 64);
    const __bf16* qh = qg + hoff;
    const __bf16* kh = kg + hoff;
    const __bf16* vh = vtg + hoff;
    char* pw = (char*)&Ps[w][0];
    const int sw7 = li & 7;

    // Q B-operand frags: qf[half] = Q[iq][32*half + 8g + j]
    bf16x8 qf[2];
#pragma unroll
    for (int half = 0; half < 2; ++half)
        qf[half] = *reinterpret_cast<const bf16x8*>(&qh[(size_t)iq * 64 + half * 32 + g * 8]);

    f32x4 o[4] = {};                          // O[d=16df+4g+r][q=li]
    float mrun = -1e30f, lrun = 0.0f;

    // stage one 64-key tile: K 8KB [64r x 128B] + V 8KB [64r x 128B], 256 threads
#define STAGE(BUF, KT) do {                                                       \
    _Pragma("unroll")                                                             \
    for (int c_ = 0; c_ < 2; ++c_) {                                              \
        const int p_ = c_ * 4096 + t * 16;                                        \
        const int row_ = p_ >> 7, sl_ = (p_ >> 4) & 7;                            \
        const int gc_ = (sl_ ^ (row_ & 7)) << 3;                                  \
        async_copy16(kh + (size_t)(((KT) << 6) + row_) * 64 + gc_,                \
                     (__bf16*)((char*)(&Ks[BUF][0]) + p_));                       \
        async_copy16(vh + (size_t)row_ * 2048 + ((KT) << 6) + gc_,                \
                     (__bf16*)((char*)(&Vs[BUF][0]) + p_));                       \
    }                                                                             \
} while (0)

    int cur = 0;
    STAGE(0, 0);
    for (int kt = 0; kt <= diag; ++kt) {
        __syncthreads();                      // buf[cur] resident; prior reads done
        if (kt < diag) STAGE(cur ^ 1, kt + 1);
        const char* kb = (char*)&Ks[cur][0];
        const char* vb = (char*)&Vs[cur][0];
        // ---- S^T = K Q^T : s[kb_][r] = S[key = 64kt+16kb_+4g+r][q = li]
        f32x4 s[4] = {};
        __builtin_amdgcn_s_setprio(1);
#pragma unroll
        for (int kb_ = 0; kb_ < 4; ++kb_) {
            const int row = kb_ * 16 + li;
#pragma unroll
            for (int half = 0; half < 2; ++half) {
                bf16x8 kf = *reinterpret_cast<const bf16x8*>(
                    kb + row * 128 + (((half * 4 + g) ^ sw7) << 4));
                s[kb_] = MFMA16(kf, qf[half], s[kb_]);
            }
        }
        __builtin_amdgcn_s_setprio(0);
        // ---- causal / padding mask (diag tile only; pad path never taken here)
        const bool pflag = (mflag[(bI * 32 + band) * 32 + kt] == 0);
        if (pflag || kt == diag) {
            const int jb = kt * 64;
#pragma unroll
            for (int kb_ = 0; kb_ < 4; ++kb_)
#pragma unroll
                for (int r = 0; r < 4; ++r) {
                    const int j0 = jb + kb_ * 16 + 4 * g + r;
                    float v0 = s[kb_][r];
                    if (j0 > iq || (pflag && mask[((size_t)(bI * 2048 + iq)) * 2048 + j0] == 0))
                        v0 = -1e30f;
                    s[kb_][r] = v0;
                }
        }
        // ---- online softmax, exp2 domain, defer-max (THR=8); reduce across 4 g-lanes
        float mt = fmaxf(fmaxf(s[0][0], s[0][1]), fmaxf(s[0][2], s[0][3]));
#pragma unroll
        for (int kb_ = 1; kb_ < 4; ++kb_) {
            mt = fmaxf(mt, fmaxf(fmaxf(s[kb_][0], s[kb_][1]), fmaxf(s[kb_][2], s[kb_][3])));
        }
        mt = fmaxf(mt, __shfl_xor(mt, 16));
        mt = fmaxf(mt, __shfl_xor(mt, 32));
        if (!__all(mt <= mrun + 8.0f)) {
            const float mn = fmaxf(mrun, mt);
            const float alpha = exp2f(mrun - mn);
#pragma unroll
            for (int df = 0; df < 4; ++df)
#pragma unroll
                for (int r = 0; r < 4; ++r) o[df][r] *= alpha;
            lrun *= alpha;
            mrun = mn;
        }
        float rs = 0.0f;
#pragma unroll
        for (int kb_ = 0; kb_ < 4; ++kb_)
#pragma unroll
            for (int r = 0; r < 4; ++r) {
                const float p = exp2f(s[kb_][r] - mrun);
                s[kb_][r] = p;
                rs += p;
            }
        rs += __shfl_xor(rs, 16);
        rs += __shfl_xor(rs, 32);
        lrun += rs;
        // ---- P -> per-wave LDS (swizzled), lands in PV B-operand layout
#pragma unroll
        for (int kb_ = 0; kb_ < 4; ++kb_) {
            const unsigned lo = packbf(s[kb_][0], s[kb_][1]);
            const unsigned hi = packbf(s[kb_][2], s[kb_][3]);
            *reinterpret_cast<uint2*>(
                pw + li * 128 + (((2 * kb_ + (g >> 1)) ^ sw7) << 4) + ((g & 1) << 3)) =
                make_uint2(lo, hi);
        }
        bf16x8 pb[2];
#pragma unroll
        for (int ks = 0; ks < 2; ++ks)
            pb[ks] = *reinterpret_cast<const bf16x8*>(
                pw + li * 128 + (((4 * ks + g) ^ sw7) << 4));
        // ---- O += V^T P : A = Vt rows (d), 8 MFMA16
        __builtin_amdgcn_s_setprio(1);
#pragma unroll
        for (int df = 0; df < 4; ++df) {
            const int vrow = df * 16 + li;
#pragma unroll
            for (int ks = 0; ks < 2; ++ks) {
                bf16x8 vf = *reinterpret_cast<const bf16x8*>(
                    vb + vrow * 128 + (((4 * ks + g) ^ sw7) << 4));
                o[df] = MFMA16(vf, pb[ks], o[df]);
            }
        }
        __builtin_amdgcn_s_setprio(0);
        cur ^= 1;
    }
#undef STAGE

    // ---- epilogue: normalize, write ao[b][iq][hI*64 + 16df + 4g + r]
    const float inv = 1.0f / lrun;
    __bf16* aor = ao + ((size_t)(bI * 2048 + iq)) * 1024 + hI * 64 + g * 4;
#pragma unroll
    for (int df = 0; df < 4; ++df) {
        bf16x4 st;
#pragma unroll
        for (int r = 0; r < 4; ++r) st[r] = (__bf16)(o[df][r] * inv);
        *reinterpret_cast<bf16x4*>(&aor[df * 16]) = st;
    }
}

// ------------------------------- launch -----------------------------------------
extern "C" void kernel_launch(void* const* d_in, const int* in_sizes, int n_in,
                              void* d_out, int out_size, void* d_ws, size_t ws_size,
                              hipStream_t stream)
{
    const float* x      = (const float*)d_in[0];
    const int*   mask   = (const int*)d_in[1];
    const float* qkv_w  = (const float*)d_in[2];
    const float* qkv_b  = (const float*)d_in[3];
    const float* proj_w = (const float*)d_in[4];
    const float* proj_b = (const float*)d_in[5];
    float* out = (float*)d_out;

    char* ws = (char*)d_ws;
    __bf16* xb    = (__bf16*)(ws + 0);          // 4096x1024        8 MB
    __bf16* wqkv  = (__bf16*)(ws + 8388608);    // 3072x1024        6 MB
    __bf16* wproj = (__bf16*)(ws + 14680064);   // 1024x1024        2 MB
    __bf16* qg    = (__bf16*)(ws + 16777216);   // [32,2048,64]     8 MB
    __bf16* kg    = (__bf16*)(ws + 25165824);   // [32,2048,64]     8 MB
    __bf16* vtg   = (__bf16*)(ws + 33554432);   // [32,64,2048]     8 MB
    __bf16* ao    = (__bf16*)(ws + 41943040);   // 4096x1024        8 MB
    int*    mflag = (int*)(ws + 50331648);      // [2,32,32]        4 KB

    f32_to_bf16_k<<<1048576 / 256, 256, 0, stream>>>(x, xb, 1048576);
    f32_to_bf16_k<<<786432 / 256, 256, 0, stream>>>(qkv_w, wqkv, 786432);
    f32_to_bf16_k<<<262144 / 256, 256, 0, stream>>>(proj_w, wproj, 262144);
    mask_reduce_k<<<2 * 32 * 32, 256, 0, stream>>>(mask, mflag);
    gemm_qkv8_k<<<192, 512, 0, stream>>>(xb, wqkv, qkv_b, qg, kg, vtg);
    attn_k<<<1024, 256, 0, stream>>>(qg, kg, vtg, mflag, mask, ao);
    gemm_proj_k<<<32 * 8, 256, 0, stream>>>(ao, wproj, proj_b, 4096, 1024, 1024, out);
}

// Round 8
// 137.915 us; speedup vs baseline: 1.3002x; 1.0019x over previous
//
#include <hip/hip_runtime.h>
#include <hip/hip_bf16.h>

// UnifiedAttention: x->QKV gemm -> causal MHA (H=16,D=64) -> proj gemm
// B=2, N=2048, C=1024. bf16 MFMA with fp32 accum throughout.

typedef __bf16 bf16x8 __attribute__((ext_vector_type(8)));
typedef __bf16 bf16x4 __attribute__((ext_vector_type(4)));
typedef __bf16 bf16x2 __attribute__((ext_vector_type(2)));
typedef float  f32x4  __attribute__((ext_vector_type(4)));
typedef float  f32x16 __attribute__((ext_vector_type(16)));
typedef int    i32x4  __attribute__((ext_vector_type(4)));

#define MFMA16(a, b, c) __builtin_amdgcn_mfma_f32_16x16x32_bf16((a), (b), (c), 0, 0, 0)

__device__ __forceinline__ void async_copy16(const __bf16* g, __bf16* l) {
    __builtin_amdgcn_global_load_lds(
        (const __attribute__((address_space(1))) void*)g,
        (__attribute__((address_space(3))) void*)l,
        16, 0, 0);
}

__device__ __forceinline__ unsigned packbf(float a, float b) {
    union { bf16x2 v; unsigned u; } un;
    un.v[0] = (__bf16)a; un.v[1] = (__bf16)b;
    return un.u;
}

// -------- fp32 -> bf16 conversion, all three tensors in one launch ------------
// counts are in float4 QUADS: x 4194304 floats = 1048576, qkv_w 3145728 = 786432,
// proj_w 1048576 = 262144. Total 2097152 quads -> 8192 blocks x 256.
__global__ void f32_to_bf16_3k(const float* __restrict__ a, __bf16* __restrict__ ad, int na,
                               const float* __restrict__ b, __bf16* __restrict__ bd, int nb,
                               const float* __restrict__ c, __bf16* __restrict__ cd, int nc)
{
    int i = blockIdx.x * blockDim.x + threadIdx.x;  // quad index
    const float* src; __bf16* dst; int j;
    if (i < na)            { src = a; dst = ad; j = i; }
    else if (i < na + nb)  { src = b; dst = bd; j = i - na; }
    else if (i < na + nb + nc) { src = c; dst = cd; j = i - na - nb; }
    else return;
    float4 v = reinterpret_cast<const float4*>(src)[j];
    bf16x4 o;
    o[0] = (__bf16)v.x; o[1] = (__bf16)v.y; o[2] = (__bf16)v.z; o[3] = (__bf16)v.w;
    reinterpret_cast<bf16x4*>(dst)[j] = o;
}

// ---------------- mask tile reduction: 64x64 tiles -> all-ones flag ----------------
__global__ void mask_reduce_k(const int* __restrict__ mask, int* __restrict__ mflag) {
    __shared__ int ok;
    const int t = threadIdx.x;
    if (t == 0) ok = 1;
    __syncthreads();
    const int jt = blockIdx.x & 31;
    const int it = (blockIdx.x >> 5) & 31;
    const int b  = blockIdx.x >> 10;
    bool all1 = true;
#pragma unroll
    for (int c = 0; c < 4; ++c) {
        const int row = c * 16 + (t >> 4);
        const int col = (t & 15) * 4;
        const int4 v = *reinterpret_cast<const int4*>(
            &mask[((size_t)(b * 2048 + it * 64 + row)) * 2048 + jt * 64 + col]);
        all1 = all1 && v.x && v.y && v.z && v.w;
    }
    if (!all1) ok = 0;
    __syncthreads();
    if (t == 0) mflag[(b * 32 + it) * 32 + jt] = ok;
}

// ============ 8-phase 256x256 QKV GEMM (T1+T2+T3+T4+T5), K=1024 =================
#define BAR() asm volatile("s_barrier" ::: "memory")
#define VM2() asm volatile("s_waitcnt vmcnt(2)" ::: "memory")

__global__ __launch_bounds__(512, 2) void gemm_qkv8_k(
    const __bf16* __restrict__ A, const __bf16* __restrict__ Bm,
    const float* __restrict__ bias,
    __bf16* __restrict__ qg, __bf16* __restrict__ kg, __bf16* __restrict__ vtg)
{
    __shared__ __align__(16) __bf16 As[2][16384];   // [buf][256 rows x 64]
    __shared__ __align__(16) __bf16 Bs[2][16384];

    const int t = threadIdx.x;
    const int lane = t & 63;
    const int w = t >> 6;
    const int wr = w >> 2, wc = w & 3;
    const int li = lane & 15, g = lane >> 4;

    // XCD-aware bijective swizzle (grid=192, 192%8==0, 24 blocks per XCD)
    const int bid = (blockIdx.x & 7) * 24 + (blockIdx.x >> 3);
    const int m0 = (bid / 12) << 8;     // N tiles = 3072/256 = 12
    const int n0 = (bid % 12) << 8;

    const int srow = t >> 3;
    const int scol = ((t & 7) ^ (srow & 7)) << 3;
    const __bf16* pA = A  + (size_t)(m0 + srow) * 1024 + scol;
    const __bf16* pB = Bm + (size_t)(n0 + srow) * 1024 + scol;
    __bf16* dA = &As[0][0] + t * 8;
    __bf16* dB = &Bs[0][0] + t * 8;

#define STAGE_A(BB, T, HH) do {                                                   \
    const size_t ro_ = (size_t)((HH) * 128) * 1024 + (size_t)(T) * 64;            \
    async_copy16(pA + ro_,         dA + (BB) * 16384 + (HH) * 8192);              \
    async_copy16(pA + ro_ + 65536, dA + (BB) * 16384 + (HH) * 8192 + 4096);       \
  } while (0)
#define STAGE_B(BB, T, HH) do {                                                   \
    const size_t ro_ = (size_t)((HH) * 128) * 1024 + (size_t)(T) * 64;            \
    async_copy16(pB + ro_,         dB + (BB) * 16384 + (HH) * 8192);              \
    async_copy16(pB + ro_ + 65536, dB + (BB) * 16384 + (HH) * 8192 + 4096);       \
  } while (0)

    const int aoff0 = ((0 + g) ^ (li & 7)) << 3;
    const int aoff1 = ((4 + g) ^ (li & 7)) << 3;
    const int abase = (wr * 128 + li) * 64;
    const int bbase = (wc * 64 + li) * 64;

    f32x4 acc[8][4] = {};
    bf16x8 a[4][2], b[2][2][2];

#define READ_A(BB, MH) do { _Pragma("unroll")                                     \
    for (int mi2 = 0; mi2 < 4; ++mi2) {                                           \
      const __bf16* p_ = &As[BB][abase + ((MH) * 4 + mi2) * 1024];                \
      a[mi2][0] = *reinterpret_cast<const bf16x8*>(p_ + aoff0);                   \
      a[mi2][1] = *reinterpret_cast<const bf16x8*>(p_ + aoff1); } } while (0)
#define READ_B(BB, NH) do { _Pragma("unroll")                                     \
    for (int ni2 = 0; ni2 < 2; ++ni2) {                                           \
      const __bf16* p_ = &Bs[BB][bbase + ((NH) * 2 + ni2) * 1024];                \
      b[NH][ni2][0] = *reinterpret_cast<const bf16x8*>(p_ + aoff0);               \
      b[NH][ni2][1] = *reinterpret_cast<const bf16x8*>(p_ + aoff1); } } while (0)
#define MFMA_QUAD(MH, NH) do {                                                    \
    __builtin_amdgcn_s_setprio(1);                                                \
    _Pragma("unroll") for (int mi2 = 0; mi2 < 4; ++mi2)                           \
    _Pragma("unroll") for (int ni2 = 0; ni2 < 2; ++ni2) {                         \
      f32x4 c_ = acc[(MH) * 4 + mi2][(NH) * 2 + ni2];                             \
      c_ = MFMA16(a[mi2][0], b[NH][ni2][0], c_);                                  \
      c_ = MFMA16(a[mi2][1], b[NH][ni2][1], c_);                                  \
      acc[(MH) * 4 + mi2][(NH) * 2 + ni2] = c_; }                                 \
    __builtin_amdgcn_s_setprio(0); } while (0)

#define KTILE(BB, T) do {                                                         \
    const int Tn_  = ((T) + 1 < 16) ? (T) + 1 : 15;                               \
    const int Tn2_ = ((T) + 2 < 16) ? (T) + 2 : 15;                               \
    STAGE_A((BB) ^ 1, Tn_, 1);                                                    \
    READ_A(BB, 0); READ_B(BB, 0);                                                 \
    BAR(); MFMA_QUAD(0, 0); BAR();                                                \
    STAGE_B((BB) ^ 1, Tn_, 0);                                                    \
    READ_B(BB, 1);                                                                \
    BAR(); MFMA_QUAD(0, 1); BAR();                                                \
    STAGE_B((BB) ^ 1, Tn_, 1);                                                    \
    READ_A(BB, 1);                                                                \
    BAR(); MFMA_QUAD(1, 0); BAR();                                                \
    STAGE_A((BB), Tn2_, 0);                                                       \
    VM2(); BAR(); MFMA_QUAD(1, 1); BAR();                                         \
  } while (0)

    STAGE_A(0, 0, 0); STAGE_A(0, 0, 1);
    STAGE_B(0, 0, 0); STAGE_B(0, 0, 1);
    STAGE_A(1, 1, 0);
    VM2(); BAR();

#pragma unroll 1
    for (int jj = 0; jj < 8; ++jj) {
        KTILE(0, 2 * jj);
        KTILE(1, 2 * jj + 1);
    }

    // ---- epilogue: scatter into q (scaled by 0.125*log2e for exp2 softmax) / k / vT
    const int nbase = n0 + wc * 64;
    const int s = nbase >> 10;
    const int headg = (m0 >> 11) * 16 + ((nbase & 1023) >> 6);
    const int mrow = (m0 & 2047) + wr * 128 + g * 4;
    float bv[4];
#pragma unroll
    for (int ni = 0; ni < 4; ++ni) bv[ni] = bias[nbase + ni * 16 + li];

    if (s == 2) {
#pragma unroll
        for (int mi = 0; mi < 8; ++mi) {
#pragma unroll
            for (int ni = 0; ni < 4; ++ni) {
                bf16x4 st;
#pragma unroll
                for (int r = 0; r < 4; ++r) st[r] = (__bf16)(acc[mi][ni][r] + bv[ni]);
                *reinterpret_cast<bf16x4*>(
                    &vtg[((size_t)(headg * 64) + ni * 16 + li) * 2048 + mrow + mi * 16]) = st;
            }
        }
    } else {
        __bf16* og = (s == 0) ? qg : kg;
        const float sc = (s == 0) ? 0.18033688f : 1.0f;   // 0.125 * log2(e)
#pragma unroll
        for (int mi = 0; mi < 8; ++mi) {
#pragma unroll
            for (int r = 0; r < 4; ++r) {
                __bf16* rp = og + ((size_t)headg * 2048 + mrow + mi * 16 + r) * 64;
#pragma unroll
                for (int ni = 0; ni < 4; ++ni)
                    rp[ni * 16 + li] = (__bf16)((acc[mi][ni][r] + bv[ni]) * sc);
            }
        }
    }
#undef KTILE
#undef MFMA_QUAD
#undef READ_A
#undef READ_B
#undef STAGE_A
#undef STAGE_B
}

// ---------------- 2-phase 128x128 GEMM (proj): C = A*Bm^T + bias, fp32 out -------
__global__ __launch_bounds__(256) void gemm_proj_k(
    const __bf16* __restrict__ A, const __bf16* __restrict__ Bm,
    const float* __restrict__ bias, int M, int N, int K,
    float* __restrict__ outf)
{
    __shared__ __align__(16) __bf16 As[128 * 64];
    __shared__ __align__(16) __bf16 Bs[128 * 64];
    const int t = threadIdx.x;
    const int nb = N >> 7;
    const int m0 = (blockIdx.x / nb) << 7;
    const int n0 = (blockIdx.x % nb) << 7;
    const int lane = t & 63, w = t >> 6;
    const int g = lane >> 4, li = lane & 15;
    const int wr = w >> 1, wc = w & 1;
    const __bf16* Ab = A + (size_t)m0 * K;
    const __bf16* Bb = Bm + (size_t)n0 * K;

    f32x4 acc[4][4] = {};

    for (int k0 = 0; k0 < K; k0 += 64) {
#pragma unroll
        for (int c = 0; c < 4; ++c) {
            const int e = (c * 256 + t) * 8;
            const int row = e >> 6;
            const int col = e & 63;
            async_copy16(Ab + (size_t)row * K + k0 + col, As + e);
            async_copy16(Bb + (size_t)row * K + k0 + col, Bs + e);
        }
        __syncthreads();
#pragma unroll
        for (int kk = 0; kk < 2; ++kk) {
            bf16x8 af[4], bf[4];
#pragma unroll
            for (int mi = 0; mi < 4; ++mi)
                af[mi] = *reinterpret_cast<const bf16x8*>(
                    &As[(wr * 64 + mi * 16 + li) * 64 + kk * 32 + g * 8]);
#pragma unroll
            for (int ni = 0; ni < 4; ++ni)
                bf[ni] = *reinterpret_cast<const bf16x8*>(
                    &Bs[(wc * 64 + ni * 16 + li) * 64 + kk * 32 + g * 8]);
#pragma unroll
            for (int mi = 0; mi < 4; ++mi)
#pragma unroll
                for (int ni = 0; ni < 4; ++ni)
                    acc[mi][ni] = MFMA16(af[mi], bf[ni], acc[mi][ni]);
        }
        __syncthreads();
    }

#pragma unroll
    for (int mi = 0; mi < 4; ++mi) {
#pragma unroll
        for (int ni = 0; ni < 4; ++ni) {
            const int n = n0 + wc * 64 + ni * 16 + li;
            const float bv = bias[n];
#pragma unroll
            for (int r = 0; r < 4; ++r) {
                const int m = m0 + wr * 64 + mi * 16 + g * 4 + r;
                outf[(size_t)m * N + n] = acc[mi][ni][r] + bv;
            }
        }
    }
}

// ------- flash attention, causal: 8 waves x 16q (128-q band), shared staging ------
// q:[BH,2048,64] (scale*log2e prefolded), k:[BH,2048,64], vT:[BH,64,2048] bf16.
// 512 blocks = (head-group, 128-q band); 8 waves x 16 queries share one staged
// 64-key K/V tile (dbuf, one __syncthreads per tile) -> staging amortized 8x,
// LDS 48KB -> 3 blocks/CU (24 waves/CU). Swapped QK^T (mfma16(K,Q)) -> softmax
// lane-local + 2 shfl (max only; lrun reduction deferred to epilogue).
// P via per-wave swizzled LDS round-trip into PV B-operand layout.
// exp2-domain + defer-max (THR=8).
__global__ __launch_bounds__(512) void attn_k(
    const __bf16* __restrict__ qg, const __bf16* __restrict__ kg,
    const __bf16* __restrict__ vtg, const int* __restrict__ mflag,
    const int* __restrict__ mask, __bf16* __restrict__ ao)
{
    __shared__ __align__(16) __bf16 Ks[2][4096];   // [64 keys][64 d], 16B-slot XOR-swz
    __shared__ __align__(16) __bf16 Vs[2][4096];   // [64 d][64 keys], XOR-swz
    __shared__ __align__(16) __bf16 Ps[8][1024];   // per-wave P [16 q][64 keys], XOR-swz
    const int t = threadIdx.x;
    const int w = t >> 6, lane = t & 63;
    const int li = lane & 15, g = lane >> 4;
    // block -> (head-group, band): XCD x owns head-groups [4x,4x+4); heavy first
    const int xcd = blockIdx.x & 7;
    const int idx = blockIdx.x >> 3;          // 0..63
    const int hg  = xcd * 4 + (idx & 3);      // 0..31
    const int band = 15 - (idx >> 2);         // 128-query band, heavy first
    const int bI = hg >> 4, hI = hg & 15;
    const int iq = band * 128 + w * 16 + li;  // this lane's query row
    const int mydiag = 2 * band + (w >> 2);   // this wave's last 64-key tile
    const int ktmax = 2 * band + 1;           // block's last staged tile
    const int rowt = 2 * band + (w >> 2);     // wave's 64-row mask tile
    const size_t hoff = (size_t)hg * (2048 * 64);
    const __bf16* qh = qg + hoff;
    const __bf16* kh = kg + hoff;
    const __bf16* vh = vtg + hoff;
    char* pw = (char*)&Ps[w][0];
    const int sw7 = li & 7;

    // Q B-operand frags: qf[half] = Q[iq][32*half + 8g + j]
    bf16x8 qf[2];
#pragma unroll
    for (int half = 0; half < 2; ++half)
        qf[half] = *reinterpret_cast<const bf16x8*>(&qh[(size_t)iq * 64 + half * 32 + g * 8]);

    f32x4 o[4] = {};                          // O[d=16df+4g+r][q=li]
    float mrun = -1e30f, lrun = 0.0f;         // lrun = per-lane partial (own keys)

    // stage one 64-key tile: K 8KB [64r x 128B] + V 8KB, 512 thr x 16B each
#define STAGE(BUF, KT) do {                                                       \
    const int p_ = t * 16;                                                        \
    const int row_ = p_ >> 7, sl_ = (p_ >> 4) & 7;                                \
    const int gc_ = (sl_ ^ (row_ & 7)) << 3;                                      \
    async_copy16(kh + (size_t)(((KT) << 6) + row_) * 64 + gc_,                    \
                 (__bf16*)((char*)(&Ks[BUF][0]) + p_));                           \
    async_copy16(vh + (size_t)row_ * 2048 + ((KT) << 6) + gc_,                    \
                 (__bf16*)((char*)(&Vs[BUF][0]) + p_));                           \
} while (0)

    int cur = 0;
    STAGE(0, 0);
    for (int kt = 0; kt <= ktmax; ++kt) {
        __syncthreads();                      // buf[cur] resident; prior reads done
        if (kt < ktmax) STAGE(cur ^ 1, kt + 1);
        if (kt <= mydiag) {
            const char* kb = (char*)&Ks[cur][0];
            const char* vb = (char*)&Vs[cur][0];
            // ---- S^T = K Q^T : s[kb_][r] = S[key = 64kt+16kb_+4g+r][q = li]
            f32x4 s[4] = {};
            __builtin_amdgcn_s_setprio(1);
#pragma unroll
            for (int kb_ = 0; kb_ < 4; ++kb_) {
                const int row = kb_ * 16 + li;
#pragma unroll
                for (int half = 0; half < 2; ++half) {
                    bf16x8 kf = *reinterpret_cast<const bf16x8*>(
                        kb + row * 128 + (((half * 4 + g) ^ sw7) << 4));
                    s[kb_] = MFMA16(kf, qf[half], s[kb_]);
                }
            }
            __builtin_amdgcn_s_setprio(0);
            // ---- causal / padding mask (diag tile only; pad path never taken here)
            const bool pflag = (mflag[(bI * 32 + rowt) * 32 + kt] == 0);
            if (pflag || kt == mydiag) {
                const int jb = kt * 64;
#pragma unroll
                for (int kb_ = 0; kb_ < 4; ++kb_)
#pragma unroll
                    for (int r = 0; r < 4; ++r) {
                        const int j0 = jb + kb_ * 16 + 4 * g + r;
                        float v0 = s[kb_][r];
                        if (j0 > iq ||
                            (pflag && mask[((size_t)(bI * 2048 + iq)) * 2048 + j0] == 0))
                            v0 = -1e30f;
                        s[kb_][r] = v0;
                    }
            }
            // ---- online softmax, exp2 domain, defer-max (THR=8)
            float mt = fmaxf(fmaxf(s[0][0], s[0][1]), fmaxf(s[0][2], s[0][3]));
#pragma unroll
            for (int kb_ = 1; kb_ < 4; ++kb_)
                mt = fmaxf(mt, fmaxf(fmaxf(s[kb_][0], s[kb_][1]),
                                     fmaxf(s[kb_][2], s[kb_][3])));
            mt = fmaxf(mt, __shfl_xor(mt, 16));
            mt = fmaxf(mt, __shfl_xor(mt, 32));
            if (!__all(mt <= mrun + 8.0f)) {
                const float mn = fmaxf(mrun, mt);
                const float alpha = exp2f(mrun - mn);
#pragma unroll
                for (int df = 0; df < 4; ++df)
#pragma unroll
                    for (int r = 0; r < 4; ++r) o[df][r] *= alpha;
                lrun *= alpha;
                mrun = mn;
            }
#pragma unroll
            for (int kb_ = 0; kb_ < 4; ++kb_)
#pragma unroll
                for (int r = 0; r < 4; ++r) {
                    const float p = exp2f(s[kb_][r] - mrun);
                    s[kb_][r] = p;
                    lrun += p;
                }
            // ---- P -> per-wave LDS (swizzled), lands in PV B-operand layout
#pragma unroll
            for (int kb_ = 0; kb_ < 4; ++kb_) {
                const unsigned lo = packbf(s[kb_][0], s[kb_][1]);
                const unsigned hi = packbf(s[kb_][2], s[kb_][3]);
                *reinterpret_cast<uint2*>(
                    pw + li * 128 + (((2 * kb_ + (g >> 1)) ^ sw7) << 4) + ((g & 1) << 3)) =
                    make_uint2(lo, hi);
            }
            bf16x8 pb[2];
#pragma unroll
            for (int ks = 0; ks < 2; ++ks)
                pb[ks] = *reinterpret_cast<const bf16x8*>(
                    pw + li * 128 + (((4 * ks + g) ^ sw7) << 4));
            // ---- O += V^T P : A = Vt rows (d), 8 MFMA16
            __builtin_amdgcn_s_setprio(1);
#pragma unroll
            for (int df = 0; df < 4; ++df) {
                const int vrow = df * 16 + li;
#pragma unroll
                for (int ks = 0; ks < 2; ++ks) {
                    bf16x8 vf = *reinterpret_cast<const bf16x8*>(
                        vb + vrow * 128 + (((4 * ks + g) ^ sw7) << 4));
                    o[df] = MFMA16(vf, pb[ks], o[df]);
                }
            }
            __builtin_amdgcn_s_setprio(0);
        }
        cur ^= 1;
    }
#undef STAGE

    // ---- epilogue: finish lrun reduction, normalize, write
    lrun += __shfl_xor(lrun, 16);
    lrun += __shfl_xor(lrun, 32);
    const float inv = 1.0f / lrun;
    __bf16* aor = ao + ((size_t)(bI * 2048 + iq)) * 1024 + hI * 64 + g * 4;
#pragma unroll
    for (int df = 0; df < 4; ++df) {
        bf16x4 st;
#pragma unroll
        for (int r = 0; r < 4; ++r) st[r] = (__bf16)(o[df][r] * inv);
        *reinterpret_cast<bf16x4*>(&aor[df * 16]) = st;
    }
}

// ------------------------------- launch -----------------------------------------
extern "C" void kernel_launch(void* const* d_in, const int* in_sizes, int n_in,
                              void* d_out, int out_size, void* d_ws, size_t ws_size,
                              hipStream_t stream)
{
    const float* x      = (const float*)d_in[0];
    const int*   mask   = (const int*)d_in[1];
    const float* qkv_w  = (const float*)d_in[2];
    const float* qkv_b  = (const float*)d_in[3];
    const float* proj_w = (const float*)d_in[4];
    const float* proj_b = (const float*)d_in[5];
    float* out = (float*)d_out;

    char* ws = (char*)d_ws;
    __bf16* xb    = (__bf16*)(ws + 0);          // 4096x1024        8 MB
    __bf16* wqkv  = (__bf16*)(ws + 8388608);    // 3072x1024        6 MB
    __bf16* wproj = (__bf16*)(ws + 14680064);   // 1024x1024        2 MB
    __bf16* qg    = (__bf16*)(ws + 16777216);   // [32,2048,64]     8 MB
    __bf16* kg    = (__bf16*)(ws + 25165824);   // [32,2048,64]     8 MB
    __bf16* vtg   = (__bf16*)(ws + 33554432);   // [32,64,2048]     8 MB
    __bf16* ao    = (__bf16*)(ws + 41943040);   // 4096x1024        8 MB
    int*    mflag = (int*)(ws + 50331648);      // [2,32,32]        4 KB

    // quad counts: 1048576 + 786432 + 262144 = 2097152 -> 8192 blocks x 256
    f32_to_bf16_3k<<<8192, 256, 0, stream>>>(x, xb, 1048576,
                                             qkv_w, wqkv, 786432,
                                             proj_w, wproj, 262144);
    mask_reduce_k<<<2 * 32 * 32, 256, 0, stream>>>(mask, mflag);
    gemm_qkv8_k<<<192, 512, 0, stream>>>(xb, wqkv, qkv_b, qg, kg, vtg);
    attn_k<<<512, 512, 0, stream>>>(qg, kg, vtg, mflag, mask, ao);
    gemm_proj_k<<<32 * 8, 256, 0, stream>>>(ao, wproj, proj_b, 4096, 1024, 1024, out);
}

// Round 10
// 134.354 us; speedup vs baseline: 1.3347x; 1.0265x over previous
//
#include <hip/hip_runtime.h>
#include <hip/hip_bf16.h>

// UnifiedAttention: x->QKV gemm -> causal MHA (H=16,D=64) -> proj gemm
// B=2, N=2048, C=1024. bf16 MFMA with fp32 accum throughout.

typedef __bf16 bf16x8 __attribute__((ext_vector_type(8)));
typedef __bf16 bf16x4 __attribute__((ext_vector_type(4)));
typedef __bf16 bf16x2 __attribute__((ext_vector_type(2)));
typedef float  f32x4  __attribute__((ext_vector_type(4)));
typedef float  f32x16 __attribute__((ext_vector_type(16)));
typedef int    i32x4  __attribute__((ext_vector_type(4)));

#define MFMA16(a, b, c) __builtin_amdgcn_mfma_f32_16x16x32_bf16((a), (b), (c), 0, 0, 0)

__device__ __forceinline__ void async_copy16(const __bf16* g, __bf16* l) {
    __builtin_amdgcn_global_load_lds(
        (const __attribute__((address_space(1))) void*)g,
        (__attribute__((address_space(3))) void*)l,
        16, 0, 0);
}

__device__ __forceinline__ unsigned packbf(float a, float b) {
    union { bf16x2 v; unsigned u; } un;
    un.v[0] = (__bf16)a; un.v[1] = (__bf16)b;
    return un.u;
}

// -------- fp32 -> bf16 conversion, all three tensors in one launch ------------
// counts in float4 QUADS: x 1048576, qkv_w 786432, proj_w 262144 -> 8192 x 256.
__global__ void f32_to_bf16_3k(const float* __restrict__ a, __bf16* __restrict__ ad, int na,
                               const float* __restrict__ b, __bf16* __restrict__ bd, int nb,
                               const float* __restrict__ c, __bf16* __restrict__ cd, int nc)
{
    int i = blockIdx.x * blockDim.x + threadIdx.x;  // quad index
    const float* src; __bf16* dst; int j;
    if (i < na)            { src = a; dst = ad; j = i; }
    else if (i < na + nb)  { src = b; dst = bd; j = i - na; }
    else if (i < na + nb + nc) { src = c; dst = cd; j = i - na - nb; }
    else return;
    float4 v = reinterpret_cast<const float4*>(src)[j];
    bf16x4 o;
    o[0] = (__bf16)v.x; o[1] = (__bf16)v.y; o[2] = (__bf16)v.z; o[3] = (__bf16)v.w;
    reinterpret_cast<bf16x4*>(dst)[j] = o;
}

// ---------------- mask tile reduction: 64x64 tiles -> all-ones flag ----------------
__global__ void mask_reduce_k(const int* __restrict__ mask, int* __restrict__ mflag) {
    __shared__ int ok;
    const int t = threadIdx.x;
    if (t == 0) ok = 1;
    __syncthreads();
    const int jt = blockIdx.x & 31;
    const int it = (blockIdx.x >> 5) & 31;
    const int b  = blockIdx.x >> 10;
    bool all1 = true;
#pragma unroll
    for (int c = 0; c < 4; ++c) {
        const int row = c * 16 + (t >> 4);
        const int col = (t & 15) * 4;
        const int4 v = *reinterpret_cast<const int4*>(
            &mask[((size_t)(b * 2048 + it * 64 + row)) * 2048 + jt * 64 + col]);
        all1 = all1 && v.x && v.y && v.z && v.w;
    }
    if (!all1) ok = 0;
    __syncthreads();
    if (t == 0) mflag[(b * 32 + it) * 32 + jt] = ok;
}

// ============ 8-phase 256x256 QKV GEMM (T1+T2+T3+T4+T5), K=1024 =================
#define BAR() asm volatile("s_barrier" ::: "memory")
#define VM2() asm volatile("s_waitcnt vmcnt(2)" ::: "memory")

__global__ __launch_bounds__(512, 2) void gemm_qkv8_k(
    const __bf16* __restrict__ A, const __bf16* __restrict__ Bm,
    const float* __restrict__ bias,
    __bf16* __restrict__ qg, __bf16* __restrict__ kg, __bf16* __restrict__ vtg)
{
    __shared__ __align__(16) __bf16 As[2][16384];   // [buf][256 rows x 64]
    __shared__ __align__(16) __bf16 Bs[2][16384];

    const int t = threadIdx.x;
    const int lane = t & 63;
    const int w = t >> 6;
    const int wr = w >> 2, wc = w & 3;
    const int li = lane & 15, g = lane >> 4;

    // XCD-aware bijective swizzle (grid=192, 192%8==0, 24 blocks per XCD)
    const int bid = (blockIdx.x & 7) * 24 + (blockIdx.x >> 3);
    const int m0 = (bid / 12) << 8;     // N tiles = 3072/256 = 12
    const int n0 = (bid % 12) << 8;

    const int srow = t >> 3;
    const int scol = ((t & 7) ^ (srow & 7)) << 3;
    const __bf16* pA = A  + (size_t)(m0 + srow) * 1024 + scol;
    const __bf16* pB = Bm + (size_t)(n0 + srow) * 1024 + scol;
    __bf16* dA = &As[0][0] + t * 8;
    __bf16* dB = &Bs[0][0] + t * 8;

#define STAGE_A(BB, T, HH) do {                                                   \
    const size_t ro_ = (size_t)((HH) * 128) * 1024 + (size_t)(T) * 64;            \
    async_copy16(pA + ro_,         dA + (BB) * 16384 + (HH) * 8192);              \
    async_copy16(pA + ro_ + 65536, dA + (BB) * 16384 + (HH) * 8192 + 4096);       \
  } while (0)
#define STAGE_B(BB, T, HH) do {                                                   \
    const size_t ro_ = (size_t)((HH) * 128) * 1024 + (size_t)(T) * 64;            \
    async_copy16(pB + ro_,         dB + (BB) * 16384 + (HH) * 8192);              \
    async_copy16(pB + ro_ + 65536, dB + (BB) * 16384 + (HH) * 8192 + 4096);       \
  } while (0)

    const int aoff0 = ((0 + g) ^ (li & 7)) << 3;
    const int aoff1 = ((4 + g) ^ (li & 7)) << 3;
    const int abase = (wr * 128 + li) * 64;
    const int bbase = (wc * 64 + li) * 64;

    f32x4 acc[8][4] = {};
    bf16x8 a[4][2], b[2][2][2];

#define READ_A(BB, MH) do { _Pragma("unroll")                                     \
    for (int mi2 = 0; mi2 < 4; ++mi2) {                                           \
      const __bf16* p_ = &As[BB][abase + ((MH) * 4 + mi2) * 1024];                \
      a[mi2][0] = *reinterpret_cast<const bf16x8*>(p_ + aoff0);                   \
      a[mi2][1] = *reinterpret_cast<const bf16x8*>(p_ + aoff1); } } while (0)
#define READ_B(BB, NH) do { _Pragma("unroll")                                     \
    for (int ni2 = 0; ni2 < 2; ++ni2) {                                           \
      const __bf16* p_ = &Bs[BB][bbase + ((NH) * 2 + ni2) * 1024];                \
      b[NH][ni2][0] = *reinterpret_cast<const bf16x8*>(p_ + aoff0);               \
      b[NH][ni2][1] = *reinterpret_cast<const bf16x8*>(p_ + aoff1); } } while (0)
#define MFMA_QUAD(MH, NH) do {                                                    \
    __builtin_amdgcn_s_setprio(1);                                                \
    _Pragma("unroll") for (int mi2 = 0; mi2 < 4; ++mi2)                           \
    _Pragma("unroll") for (int ni2 = 0; ni2 < 2; ++ni2) {                         \
      f32x4 c_ = acc[(MH) * 4 + mi2][(NH) * 2 + ni2];                             \
      c_ = MFMA16(a[mi2][0], b[NH][ni2][0], c_);                                  \
      c_ = MFMA16(a[mi2][1], b[NH][ni2][1], c_);                                  \
      acc[(MH) * 4 + mi2][(NH) * 2 + ni2] = c_; }                                 \
    __builtin_amdgcn_s_setprio(0); } while (0)

#define KTILE(BB, T) do {                                                         \
    const int Tn_  = ((T) + 1 < 16) ? (T) + 1 : 15;                               \
    const int Tn2_ = ((T) + 2 < 16) ? (T) + 2 : 15;                               \
    STAGE_A((BB) ^ 1, Tn_, 1);                                                    \
    READ_A(BB, 0); READ_B(BB, 0);                                                 \
    BAR(); MFMA_QUAD(0, 0); BAR();                                                \
    STAGE_B((BB) ^ 1, Tn_, 0);                                                    \
    READ_B(BB, 1);                                                                \
    BAR(); MFMA_QUAD(0, 1); BAR();                                                \
    STAGE_B((BB) ^ 1, Tn_, 1);                                                    \
    READ_A(BB, 1);                                                                \
    BAR(); MFMA_QUAD(1, 0); BAR();                                                \
    STAGE_A((BB), Tn2_, 0);                                                       \
    VM2(); BAR(); MFMA_QUAD(1, 1); BAR();                                         \
  } while (0)

    STAGE_A(0, 0, 0); STAGE_A(0, 0, 1);
    STAGE_B(0, 0, 0); STAGE_B(0, 0, 1);
    STAGE_A(1, 1, 0);
    VM2(); BAR();

#pragma unroll 1
    for (int jj = 0; jj < 8; ++jj) {
        KTILE(0, 2 * jj);
        KTILE(1, 2 * jj + 1);
    }

    // ---- epilogue: scatter into q (scaled by 0.125*log2e for exp2 softmax) / k / vT
    const int nbase = n0 + wc * 64;
    const int s = nbase >> 10;
    const int headg = (m0 >> 11) * 16 + ((nbase & 1023) >> 6);
    const int mrow = (m0 & 2047) + wr * 128 + g * 4;
    float bv[4];
#pragma unroll
    for (int ni = 0; ni < 4; ++ni) bv[ni] = bias[nbase + ni * 16 + li];

    if (s == 2) {
#pragma unroll
        for (int mi = 0; mi < 8; ++mi) {
#pragma unroll
            for (int ni = 0; ni < 4; ++ni) {
                bf16x4 st;
#pragma unroll
                for (int r = 0; r < 4; ++r) st[r] = (__bf16)(acc[mi][ni][r] + bv[ni]);
                *reinterpret_cast<bf16x4*>(
                    &vtg[((size_t)(headg * 64) + ni * 16 + li) * 2048 + mrow + mi * 16]) = st;
            }
        }
    } else {
        __bf16* og = (s == 0) ? qg : kg;
        const float sc = (s == 0) ? 0.18033688f : 1.0f;   // 0.125 * log2(e)
#pragma unroll
        for (int mi = 0; mi < 8; ++mi) {
#pragma unroll
            for (int r = 0; r < 4; ++r) {
                __bf16* rp = og + ((size_t)headg * 2048 + mrow + mi * 16 + r) * 64;
#pragma unroll
                for (int ni = 0; ni < 4; ++ni)
                    rp[ni * 16 + li] = (__bf16)((acc[mi][ni][r] + bv[ni]) * sc);
            }
        }
    }
#undef KTILE
#undef MFMA_QUAD
#undef READ_A
#undef READ_B
#undef STAGE_A
#undef STAGE_B
}

// ---------------- 2-phase 128x128 GEMM (proj): C = A*Bm^T + bias, fp32 out -------
__global__ __launch_bounds__(256) void gemm_proj_k(
    const __bf16* __restrict__ A, const __bf16* __restrict__ Bm,
    const float* __restrict__ bias, int M, int N, int K,
    float* __restrict__ outf)
{
    __shared__ __align__(16) __bf16 As[128 * 64];
    __shared__ __align__(16) __bf16 Bs[128 * 64];
    const int t = threadIdx.x;
    const int nb = N >> 7;
    const int m0 = (blockIdx.x / nb) << 7;
    const int n0 = (blockIdx.x % nb) << 7;
    const int lane = t & 63, w = t >> 6;
    const int g = lane >> 4, li = lane & 15;
    const int wr = w >> 1, wc = w & 1;
    const __bf16* Ab = A + (size_t)m0 * K;
    const __bf16* Bb = Bm + (size_t)n0 * K;

    f32x4 acc[4][4] = {};

    for (int k0 = 0; k0 < K; k0 += 64) {
#pragma unroll
        for (int c = 0; c < 4; ++c) {
            const int e = (c * 256 + t) * 8;
            const int row = e >> 6;
            const int col = e & 63;
            async_copy16(Ab + (size_t)row * K + k0 + col, As + e);
            async_copy16(Bb + (size_t)row * K + k0 + col, Bs + e);
        }
        __syncthreads();
#pragma unroll
        for (int kk = 0; kk < 2; ++kk) {
            bf16x8 af[4], bf[4];
#pragma unroll
            for (int mi = 0; mi < 4; ++mi)
                af[mi] = *reinterpret_cast<const bf16x8*>(
                    &As[(wr * 64 + mi * 16 + li) * 64 + kk * 32 + g * 8]);
#pragma unroll
            for (int ni = 0; ni < 4; ++ni)
                bf[ni] = *reinterpret_cast<const bf16x8*>(
                    &Bs[(wc * 64 + ni * 16 + li) * 64 + kk * 32 + g * 8]);
#pragma unroll
            for (int mi = 0; mi < 4; ++mi)
#pragma unroll
                for (int ni = 0; ni < 4; ++ni)
                    acc[mi][ni] = MFMA16(af[mi], bf[ni], acc[mi][ni]);
        }
        __syncthreads();
    }

#pragma unroll
    for (int mi = 0; mi < 4; ++mi) {
#pragma unroll
        for (int ni = 0; ni < 4; ++ni) {
            const int n = n0 + wc * 64 + ni * 16 + li;
            const float bv = bias[n];
#pragma unroll
            for (int r = 0; r < 4; ++r) {
                const int m = m0 + wr * 64 + mi * 16 + g * 4 + r;
                outf[(size_t)m * N + n] = acc[mi][ni][r] + bv;
            }
        }
    }
}

// ------- flash attention, causal: 8 waves x 16q, QUAD-buffer counted-vmcnt --------
// q:[BH,2048,64] (scale*log2e prefolded), k:[BH,2048,64], vT:[BH,64,2048] bf16.
// 512 blocks = (head-group, 128-q band); 8 waves x 16 queries share staged 64-key
// K/V tiles. T4 discipline: STAGE(kt+2) -> vmcnt(2) -> raw s_barrier (never
// vmcnt(0) in main loop). 4 buffers (NOT 3): stage at interval kt targets tile
// kt-2's buffer, whose readers provably finished before barrier kt-1 which the
// staging wave already crossed -> no WAR race (3-buffer version raced: r9).
// Swapped QK^T (mfma16(K,Q)) -> lane-local softmax + 2 shfl (max only; lrun
// reduction deferred to epilogue). P via per-wave swizzled LDS round-trip.
// exp2-domain + defer-max (THR=8). LDS = 4*16KB + 16KB = 80KB -> 2 blocks/CU.
__global__ __launch_bounds__(512) void attn_k(
    const __bf16* __restrict__ qg, const __bf16* __restrict__ kg,
    const __bf16* __restrict__ vtg, const int* __restrict__ mflag,
    const int* __restrict__ mask, __bf16* __restrict__ ao)
{
    __shared__ __align__(16) __bf16 Ks[4][4096];   // [64 keys][64 d], 16B-slot XOR-swz
    __shared__ __align__(16) __bf16 Vs[4][4096];   // [64 d][64 keys], XOR-swz
    __shared__ __align__(16) __bf16 Ps[8][1024];   // per-wave P [16 q][64 keys], XOR-swz
    const int t = threadIdx.x;
    const int w = t >> 6, lane = t & 63;
    const int li = lane & 15, g = lane >> 4;
    // block -> (head-group, band): XCD x owns head-groups [4x,4x+4); heavy first
    const int xcd = blockIdx.x & 7;
    const int idx = blockIdx.x >> 3;          // 0..63
    const int hg  = xcd * 4 + (idx & 3);      // 0..31
    const int band = 15 - (idx >> 2);         // 128-query band, heavy first
    const int bI = hg >> 4, hI = hg & 15;
    const int iq = band * 128 + w * 16 + li;  // this lane's query row
    const int mydiag = 2 * band + (w >> 2);   // this wave's last 64-key tile
    const int ktmax = 2 * band + 1;           // block's last staged tile (>=1)
    const int rowt = 2 * band + (w >> 2);     // wave's 64-row mask tile
    const size_t hoff = (size_t)hg * (2048 * 64);
    const __bf16* qh = qg + hoff;
    const __bf16* kh = kg + hoff;
    const __bf16* vh = vtg + hoff;
    char* pw = (char*)&Ps[w][0];
    const int sw7 = li & 7;

    // Q B-operand frags: qf[half] = Q[iq][32*half + 8g + j]
    bf16x8 qf[2];
#pragma unroll
    for (int half = 0; half < 2; ++half)
        qf[half] = *reinterpret_cast<const bf16x8*>(&qh[(size_t)iq * 64 + half * 32 + g * 8]);

    f32x4 o[4] = {};                          // O[d=16df+4g+r][q=li]
    float mrun = -1e30f, lrun = 0.0f;         // lrun = per-lane partial (own keys)

    // stage one 64-key tile into buffer BUF: K 8KB + V 8KB, 512 thr x 16B each
#define STAGE(BUF, KT) do {                                                       \
    const int p_ = t * 16;                                                        \
    const int row_ = p_ >> 7, sl_ = (p_ >> 4) & 7;                                \
    const int gc_ = (sl_ ^ (row_ & 7)) << 3;                                      \
    async_copy16(kh + (size_t)(((KT) << 6) + row_) * 64 + gc_,                    \
                 (__bf16*)((char*)(&Ks[0][0]) + (BUF) * 8192 + p_));              \
    async_copy16(vh + (size_t)row_ * 2048 + ((KT) << 6) + gc_,                    \
                 (__bf16*)((char*)(&Vs[0][0]) + (BUF) * 8192 + p_));              \
} while (0)

    // prologue: tiles 0,1 in flight; vmcnt(2) -> tile 0 landed; barrier.
    STAGE(0, 0);
    STAGE(1, 1);
    VM2();
    __builtin_amdgcn_s_barrier();

    int cur = 0;
    for (int kt = 0; kt <= ktmax; ++kt) {
        // T4: stage 2 ahead into buffer (cur+2)&3 (tile kt-2's buffer -- all its
        // readers finished before barrier kt-1, already crossed). Counted wait
        // ensures tile kt+1 landed; tile kt was ensured last interval.
        if (kt + 2 <= ktmax) {
            STAGE((cur + 2) & 3, kt + 2);
            VM2();
        } else {
            asm volatile("s_waitcnt vmcnt(0)" ::: "memory");   // tail only
        }
        __builtin_amdgcn_sched_barrier(0);
        __builtin_amdgcn_s_barrier();
        __builtin_amdgcn_sched_barrier(0);
        if (kt <= mydiag) {
            const char* kb = (char*)&Ks[0][0] + cur * 8192;
            const char* vb = (char*)&Vs[0][0] + cur * 8192;
            // ---- S^T = K Q^T : s[kb_][r] = S[key = 64kt+16kb_+4g+r][q = li]
            f32x4 s[4] = {};
            __builtin_amdgcn_s_setprio(1);
#pragma unroll
            for (int kb_ = 0; kb_ < 4; ++kb_) {
                const int row = kb_ * 16 + li;
#pragma unroll
                for (int half = 0; half < 2; ++half) {
                    bf16x8 kf = *reinterpret_cast<const bf16x8*>(
                        kb + row * 128 + (((half * 4 + g) ^ sw7) << 4));
                    s[kb_] = MFMA16(kf, qf[half], s[kb_]);
                }
            }
            __builtin_amdgcn_s_setprio(0);
            // ---- causal / padding mask (diag tile only; pad path never taken here)
            const bool pflag = (mflag[(bI * 32 + rowt) * 32 + kt] == 0);
            if (pflag || kt == mydiag) {
                const int jb = kt * 64;
#pragma unroll
                for (int kb_ = 0; kb_ < 4; ++kb_)
#pragma unroll
                    for (int r = 0; r < 4; ++r) {
                        const int j0 = jb + kb_ * 16 + 4 * g + r;
                        float v0 = s[kb_][r];
                        if (j0 > iq ||
                            (pflag && mask[((size_t)(bI * 2048 + iq)) * 2048 + j0] == 0))
                            v0 = -1e30f;
                        s[kb_][r] = v0;
                    }
            }
            // ---- online softmax, exp2 domain, defer-max (THR=8)
            float mt = fmaxf(fmaxf(s[0][0], s[0][1]), fmaxf(s[0][2], s[0][3]));
#pragma unroll
            for (int kb_ = 1; kb_ < 4; ++kb_)
                mt = fmaxf(mt, fmaxf(fmaxf(s[kb_][0], s[kb_][1]),
                                     fmaxf(s[kb_][2], s[kb_][3])));
            mt = fmaxf(mt, __shfl_xor(mt, 16));
            mt = fmaxf(mt, __shfl_xor(mt, 32));
            if (!__all(mt <= mrun + 8.0f)) {
                const float mn = fmaxf(mrun, mt);
                const float alpha = exp2f(mrun - mn);
#pragma unroll
                for (int df = 0; df < 4; ++df)
#pragma unroll
                    for (int r = 0; r < 4; ++r) o[df][r] *= alpha;
                lrun *= alpha;
                mrun = mn;
            }
#pragma unroll
            for (int kb_ = 0; kb_ < 4; ++kb_)
#pragma unroll
                for (int r = 0; r < 4; ++r) {
                    const float p = exp2f(s[kb_][r] - mrun);
                    s[kb_][r] = p;
                    lrun += p;
                }
            // ---- P -> per-wave LDS (swizzled), lands in PV B-operand layout
#pragma unroll
            for (int kb_ = 0; kb_ < 4; ++kb_) {
                const unsigned lo = packbf(s[kb_][0], s[kb_][1]);
                const unsigned hi = packbf(s[kb_][2], s[kb_][3]);
                *reinterpret_cast<uint2*>(
                    pw + li * 128 + (((2 * kb_ + (g >> 1)) ^ sw7) << 4) + ((g & 1) << 3)) =
                    make_uint2(lo, hi);
            }
            bf16x8 pb[2];
#pragma unroll
            for (int ks = 0; ks < 2; ++ks)
                pb[ks] = *reinterpret_cast<const bf16x8*>(
                    pw + li * 128 + (((4 * ks + g) ^ sw7) << 4));
            // ---- O += V^T P : A = Vt rows (d), 8 MFMA16
            __builtin_amdgcn_s_setprio(1);
#pragma unroll
            for (int df = 0; df < 4; ++df) {
                const int vrow = df * 16 + li;
#pragma unroll
                for (int ks = 0; ks < 2; ++ks) {
                    bf16x8 vf = *reinterpret_cast<const bf16x8*>(
                        vb + vrow * 128 + (((4 * ks + g) ^ sw7) << 4));
                    o[df] = MFMA16(vf, pb[ks], o[df]);
                }
            }
            __builtin_amdgcn_s_setprio(0);
        }
        cur = (cur + 1) & 3;
    }
#undef STAGE

    // ---- epilogue: finish lrun reduction, normalize, write
    lrun += __shfl_xor(lrun, 16);
    lrun += __shfl_xor(lrun, 32);
    const float inv = 1.0f / lrun;
    __bf16* aor = ao + ((size_t)(bI * 2048 + iq)) * 1024 + hI * 64 + g * 4;
#pragma unroll
    for (int df = 0; df < 4; ++df) {
        bf16x4 st;
#pragma unroll
        for (int r = 0; r < 4; ++r) st[r] = (__bf16)(o[df][r] * inv);
        *reinterpret_cast<bf16x4*>(&aor[df * 16]) = st;
    }
}

// ------------------------------- launch -----------------------------------------
extern "C" void kernel_launch(void* const* d_in, const int* in_sizes, int n_in,
                              void* d_out, int out_size, void* d_ws, size_t ws_size,
                              hipStream_t stream)
{
    const float* x      = (const float*)d_in[0];
    const int*   mask   = (const int*)d_in[1];
    const float* qkv_w  = (const float*)d_in[2];
    const float* qkv_b  = (const float*)d_in[3];
    const float* proj_w = (const float*)d_in[4];
    const float* proj_b = (const float*)d_in[5];
    float* out = (float*)d_out;

    char* ws = (char*)d_ws;
    __bf16* xb    = (__bf16*)(ws + 0);          // 4096x1024        8 MB
    __bf16* wqkv  = (__bf16*)(ws + 8388608);    // 3072x1024        6 MB
    __bf16* wproj = (__bf16*)(ws + 14680064);   // 1024x1024        2 MB
    __bf16* qg    = (__bf16*)(ws + 16777216);   // [32,2048,64]     8 MB
    __bf16* kg    = (__bf16*)(ws + 25165824);   // [32,2048,64]     8 MB
    __bf16* vtg   = (__bf16*)(ws + 33554432);   // [32,64,2048]     8 MB
    __bf16* ao    = (__bf16*)(ws + 41943040);   // 4096x1024        8 MB
    int*    mflag = (int*)(ws + 50331648);      // [2,32,32]        4 KB

    // quad counts: 1048576 + 786432 + 262144 = 2097152 -> 8192 blocks x 256
    f32_to_bf16_3k<<<8192, 256, 0, stream>>>(x, xb, 1048576,
                                             qkv_w, wqkv, 786432,
                                             proj_w, wproj, 262144);
    mask_reduce_k<<<2 * 32 * 32, 256, 0, stream>>>(mask, mflag);
    gemm_qkv8_k<<<192, 512, 0, stream>>>(xb, wqkv, qkv_b, qg, kg, vtg);
    attn_k<<<512, 512, 0, stream>>>(qg, kg, vtg, mflag, mask, ao);
    gemm_proj_k<<<32 * 8, 256, 0, stream>>>(ao, wproj, proj_b, 4096, 1024, 1024, out);
}

// Round 11
// 134.164 us; speedup vs baseline: 1.3366x; 1.0014x over previous
//
#include <hip/hip_runtime.h>
#include <hip/hip_bf16.h>

// UnifiedAttention: x->QKV gemm -> causal MHA (H=16,D=64) -> proj gemm
// B=2, N=2048, C=1024. bf16 MFMA with fp32 accum throughout.

typedef __bf16 bf16x8 __attribute__((ext_vector_type(8)));
typedef __bf16 bf16x4 __attribute__((ext_vector_type(4)));
typedef __bf16 bf16x2 __attribute__((ext_vector_type(2)));
typedef float  f32x4  __attribute__((ext_vector_type(4)));
typedef float  f32x16 __attribute__((ext_vector_type(16)));
typedef int    i32x4  __attribute__((ext_vector_type(4)));

#define MFMA16(a, b, c) __builtin_amdgcn_mfma_f32_16x16x32_bf16((a), (b), (c), 0, 0, 0)

__device__ __forceinline__ void async_copy16(const __bf16* g, __bf16* l) {
    __builtin_amdgcn_global_load_lds(
        (const __attribute__((address_space(1))) void*)g,
        (__attribute__((address_space(3))) void*)l,
        16, 0, 0);
}

__device__ __forceinline__ unsigned packbf(float a, float b) {
    union { bf16x2 v; unsigned u; } un;
    un.v[0] = (__bf16)a; un.v[1] = (__bf16)b;
    return un.u;
}

// -------- fp32 -> bf16 conversion, all three tensors in one launch ------------
// counts in float4 QUADS: x 1048576, qkv_w 786432, proj_w 262144 -> 8192 x 256.
__global__ void f32_to_bf16_3k(const float* __restrict__ a, __bf16* __restrict__ ad, int na,
                               const float* __restrict__ b, __bf16* __restrict__ bd, int nb,
                               const float* __restrict__ c, __bf16* __restrict__ cd, int nc)
{
    int i = blockIdx.x * blockDim.x + threadIdx.x;  // quad index
    const float* src; __bf16* dst; int j;
    if (i < na)            { src = a; dst = ad; j = i; }
    else if (i < na + nb)  { src = b; dst = bd; j = i - na; }
    else if (i < na + nb + nc) { src = c; dst = cd; j = i - na - nb; }
    else return;
    float4 v = reinterpret_cast<const float4*>(src)[j];
    bf16x4 o;
    o[0] = (__bf16)v.x; o[1] = (__bf16)v.y; o[2] = (__bf16)v.z; o[3] = (__bf16)v.w;
    reinterpret_cast<bf16x4*>(dst)[j] = o;
}

// ---------------- mask tile reduction: 64x64 tiles -> all-ones flag ----------------
__global__ void mask_reduce_k(const int* __restrict__ mask, int* __restrict__ mflag) {
    __shared__ int ok;
    const int t = threadIdx.x;
    if (t == 0) ok = 1;
    __syncthreads();
    const int jt = blockIdx.x & 31;
    const int it = (blockIdx.x >> 5) & 31;
    const int b  = blockIdx.x >> 10;
    bool all1 = true;
#pragma unroll
    for (int c = 0; c < 4; ++c) {
        const int row = c * 16 + (t >> 4);
        const int col = (t & 15) * 4;
        const int4 v = *reinterpret_cast<const int4*>(
            &mask[((size_t)(b * 2048 + it * 64 + row)) * 2048 + jt * 64 + col]);
        all1 = all1 && v.x && v.y && v.z && v.w;
    }
    if (!all1) ok = 0;
    __syncthreads();
    if (t == 0) mflag[(b * 32 + it) * 32 + jt] = ok;
}

// ============ 8-phase 256x256 QKV GEMM (T1+T2+T3+T4+T5), K=1024 =================
#define BAR() asm volatile("s_barrier" ::: "memory")
#define VM2() asm volatile("s_waitcnt vmcnt(2)" ::: "memory")

__global__ __launch_bounds__(512, 2) void gemm_qkv8_k(
    const __bf16* __restrict__ A, const __bf16* __restrict__ Bm,
    const float* __restrict__ bias,
    __bf16* __restrict__ qg, __bf16* __restrict__ kg, __bf16* __restrict__ vtg)
{
    __shared__ __align__(16) __bf16 As[2][16384];   // [buf][256 rows x 64]
    __shared__ __align__(16) __bf16 Bs[2][16384];

    const int t = threadIdx.x;
    const int lane = t & 63;
    const int w = t >> 6;
    const int wr = w >> 2, wc = w & 3;
    const int li = lane & 15, g = lane >> 4;

    // XCD-aware bijective swizzle (grid=192, 192%8==0, 24 blocks per XCD)
    const int bid = (blockIdx.x & 7) * 24 + (blockIdx.x >> 3);
    const int m0 = (bid / 12) << 8;     // N tiles = 3072/256 = 12
    const int n0 = (bid % 12) << 8;

    const int srow = t >> 3;
    const int scol = ((t & 7) ^ (srow & 7)) << 3;
    const __bf16* pA = A  + (size_t)(m0 + srow) * 1024 + scol;
    const __bf16* pB = Bm + (size_t)(n0 + srow) * 1024 + scol;
    __bf16* dA = &As[0][0] + t * 8;
    __bf16* dB = &Bs[0][0] + t * 8;

#define STAGE_A(BB, T, HH) do {                                                   \
    const size_t ro_ = (size_t)((HH) * 128) * 1024 + (size_t)(T) * 64;            \
    async_copy16(pA + ro_,         dA + (BB) * 16384 + (HH) * 8192);              \
    async_copy16(pA + ro_ + 65536, dA + (BB) * 16384 + (HH) * 8192 + 4096);       \
  } while (0)
#define STAGE_B(BB, T, HH) do {                                                   \
    const size_t ro_ = (size_t)((HH) * 128) * 1024 + (size_t)(T) * 64;            \
    async_copy16(pB + ro_,         dB + (BB) * 16384 + (HH) * 8192);              \
    async_copy16(pB + ro_ + 65536, dB + (BB) * 16384 + (HH) * 8192 + 4096);       \
  } while (0)

    const int aoff0 = ((0 + g) ^ (li & 7)) << 3;
    const int aoff1 = ((4 + g) ^ (li & 7)) << 3;
    const int abase = (wr * 128 + li) * 64;
    const int bbase = (wc * 64 + li) * 64;

    f32x4 acc[8][4] = {};
    bf16x8 a[4][2], b[2][2][2];

#define READ_A(BB, MH) do { _Pragma("unroll")                                     \
    for (int mi2 = 0; mi2 < 4; ++mi2) {                                           \
      const __bf16* p_ = &As[BB][abase + ((MH) * 4 + mi2) * 1024];                \
      a[mi2][0] = *reinterpret_cast<const bf16x8*>(p_ + aoff0);                   \
      a[mi2][1] = *reinterpret_cast<const bf16x8*>(p_ + aoff1); } } while (0)
#define READ_B(BB, NH) do { _Pragma("unroll")                                     \
    for (int ni2 = 0; ni2 < 2; ++ni2) {                                           \
      const __bf16* p_ = &Bs[BB][bbase + ((NH) * 2 + ni2) * 1024];                \
      b[NH][ni2][0] = *reinterpret_cast<const bf16x8*>(p_ + aoff0);               \
      b[NH][ni2][1] = *reinterpret_cast<const bf16x8*>(p_ + aoff1); } } while (0)
#define MFMA_QUAD(MH, NH) do {                                                    \
    __builtin_amdgcn_s_setprio(1);                                                \
    _Pragma("unroll") for (int mi2 = 0; mi2 < 4; ++mi2)                           \
    _Pragma("unroll") for (int ni2 = 0; ni2 < 2; ++ni2) {                         \
      f32x4 c_ = acc[(MH) * 4 + mi2][(NH) * 2 + ni2];                             \
      c_ = MFMA16(a[mi2][0], b[NH][ni2][0], c_);                                  \
      c_ = MFMA16(a[mi2][1], b[NH][ni2][1], c_);                                  \
      acc[(MH) * 4 + mi2][(NH) * 2 + ni2] = c_; }                                 \
    __builtin_amdgcn_s_setprio(0); } while (0)

#define KTILE(BB, T) do {                                                         \
    const int Tn_  = ((T) + 1 < 16) ? (T) + 1 : 15;                               \
    const int Tn2_ = ((T) + 2 < 16) ? (T) + 2 : 15;                               \
    STAGE_A((BB) ^ 1, Tn_, 1);                                                    \
    READ_A(BB, 0); READ_B(BB, 0);                                                 \
    BAR(); MFMA_QUAD(0, 0); BAR();                                                \
    STAGE_B((BB) ^ 1, Tn_, 0);                                                    \
    READ_B(BB, 1);                                                                \
    BAR(); MFMA_QUAD(0, 1); BAR();                                                \
    STAGE_B((BB) ^ 1, Tn_, 1);                                                    \
    READ_A(BB, 1);                                                                \
    BAR(); MFMA_QUAD(1, 0); BAR();                                                \
    STAGE_A((BB), Tn2_, 0);                                                       \
    VM2(); BAR(); MFMA_QUAD(1, 1); BAR();                                         \
  } while (0)

    STAGE_A(0, 0, 0); STAGE_A(0, 0, 1);
    STAGE_B(0, 0, 0); STAGE_B(0, 0, 1);
    STAGE_A(1, 1, 0);
    VM2(); BAR();

#pragma unroll 1
    for (int jj = 0; jj < 8; ++jj) {
        KTILE(0, 2 * jj);
        KTILE(1, 2 * jj + 1);
    }

    // ---- epilogue: scatter into q (scaled by 0.125*log2e for exp2 softmax) / k / vT
    const int nbase = n0 + wc * 64;
    const int s = nbase >> 10;
    const int headg = (m0 >> 11) * 16 + ((nbase & 1023) >> 6);
    const int mrow = (m0 & 2047) + wr * 128 + g * 4;
    float bv[4];
#pragma unroll
    for (int ni = 0; ni < 4; ++ni) bv[ni] = bias[nbase + ni * 16 + li];

    if (s == 2) {
#pragma unroll
        for (int mi = 0; mi < 8; ++mi) {
#pragma unroll
            for (int ni = 0; ni < 4; ++ni) {
                bf16x4 st;
#pragma unroll
                for (int r = 0; r < 4; ++r) st[r] = (__bf16)(acc[mi][ni][r] + bv[ni]);
                *reinterpret_cast<bf16x4*>(
                    &vtg[((size_t)(headg * 64) + ni * 16 + li) * 2048 + mrow + mi * 16]) = st;
            }
        }
    } else {
        __bf16* og = (s == 0) ? qg : kg;
        const float sc = (s == 0) ? 0.18033688f : 1.0f;   // 0.125 * log2(e)
#pragma unroll
        for (int mi = 0; mi < 8; ++mi) {
#pragma unroll
            for (int r = 0; r < 4; ++r) {
                __bf16* rp = og + ((size_t)headg * 2048 + mrow + mi * 16 + r) * 64;
#pragma unroll
                for (int ni = 0; ni < 4; ++ni)
                    rp[ni * 16 + li] = (__bf16)((acc[mi][ni][r] + bv[ni]) * sc);
            }
        }
    }
#undef KTILE
#undef MFMA_QUAD
#undef READ_A
#undef READ_B
#undef STAGE_A
#undef STAGE_B
}

// ---------------- 2-phase 128x128 GEMM (proj): C = A*Bm^T + bias, fp32 out -------
__global__ __launch_bounds__(256) void gemm_proj_k(
    const __bf16* __restrict__ A, const __bf16* __restrict__ Bm,
    const float* __restrict__ bias, int M, int N, int K,
    float* __restrict__ outf)
{
    __shared__ __align__(16) __bf16 As[128 * 64];
    __shared__ __align__(16) __bf16 Bs[128 * 64];
    const int t = threadIdx.x;
    const int nb = N >> 7;
    const int m0 = (blockIdx.x / nb) << 7;
    const int n0 = (blockIdx.x % nb) << 7;
    const int lane = t & 63, w = t >> 6;
    const int g = lane >> 4, li = lane & 15;
    const int wr = w >> 1, wc = w & 1;
    const __bf16* Ab = A + (size_t)m0 * K;
    const __bf16* Bb = Bm + (size_t)n0 * K;

    f32x4 acc[4][4] = {};

    for (int k0 = 0; k0 < K; k0 += 64) {
#pragma unroll
        for (int c = 0; c < 4; ++c) {
            const int e = (c * 256 + t) * 8;
            const int row = e >> 6;
            const int col = e & 63;
            async_copy16(Ab + (size_t)row * K + k0 + col, As + e);
            async_copy16(Bb + (size_t)row * K + k0 + col, Bs + e);
        }
        __syncthreads();
#pragma unroll
        for (int kk = 0; kk < 2; ++kk) {
            bf16x8 af[4], bf[4];
#pragma unroll
            for (int mi = 0; mi < 4; ++mi)
                af[mi] = *reinterpret_cast<const bf16x8*>(
                    &As[(wr * 64 + mi * 16 + li) * 64 + kk * 32 + g * 8]);
#pragma unroll
            for (int ni = 0; ni < 4; ++ni)
                bf[ni] = *reinterpret_cast<const bf16x8*>(
                    &Bs[(wc * 64 + ni * 16 + li) * 64 + kk * 32 + g * 8]);
#pragma unroll
            for (int mi = 0; mi < 4; ++mi)
#pragma unroll
                for (int ni = 0; ni < 4; ++ni)
                    acc[mi][ni] = MFMA16(af[mi], bf[ni], acc[mi][ni]);
        }
        __syncthreads();
    }

#pragma unroll
    for (int mi = 0; mi < 4; ++mi) {
#pragma unroll
        for (int ni = 0; ni < 4; ++ni) {
            const int n = n0 + wc * 64 + ni * 16 + li;
            const float bv = bias[n];
#pragma unroll
            for (int r = 0; r < 4; ++r) {
                const int m = m0 + wr * 64 + mi * 16 + g * 4 + r;
                outf[(size_t)m * N + n] = acc[mi][ni][r] + bv;
            }
        }
    }
}

// ------- flash attention, causal: 8 waves x 16q, QUAD-buffer counted-vmcnt --------
// q:[BH,2048,64] (scale*log2e prefolded), k:[BH,2048,64], vT:[BH,64,2048] bf16.
// 512 blocks = (head-group, 128-q band); 8 waves x 16 queries share staged 64-key
// K/V tiles. T4 discipline: STAGE(kt+2) -> vmcnt(2) -> raw s_barrier (never
// vmcnt(0) in main loop). 4 buffers (NOT 3): stage at interval kt targets tile
// kt-2's buffer, whose readers provably finished before barrier kt-1 which the
// staging wave already crossed -> no WAR race (3-buffer version raced: r9).
// Swapped QK^T (mfma16(K,Q)) -> lane-local softmax + 2 shfl (max only; lrun
// reduction deferred to epilogue). P via per-wave swizzled LDS round-trip.
// exp2-domain + defer-max (THR=8). LDS = 4*16KB + 16KB = 80KB -> 2 blocks/CU.
__global__ __launch_bounds__(512) void attn_k(
    const __bf16* __restrict__ qg, const __bf16* __restrict__ kg,
    const __bf16* __restrict__ vtg, const int* __restrict__ mflag,
    const int* __restrict__ mask, __bf16* __restrict__ ao)
{
    __shared__ __align__(16) __bf16 Ks[4][4096];   // [64 keys][64 d], 16B-slot XOR-swz
    __shared__ __align__(16) __bf16 Vs[4][4096];   // [64 d][64 keys], XOR-swz
    __shared__ __align__(16) __bf16 Ps[8][1024];   // per-wave P [16 q][64 keys], XOR-swz
    const int t = threadIdx.x;
    const int w = t >> 6, lane = t & 63;
    const int li = lane & 15, g = lane >> 4;
    // block -> (head-group, band): XCD x owns head-groups [4x,4x+4); heavy first
    const int xcd = blockIdx.x & 7;
    const int idx = blockIdx.x >> 3;          // 0..63
    const int hg  = xcd * 4 + (idx & 3);      // 0..31
    const int band = 15 - (idx >> 2);         // 128-query band, heavy first
    const int bI = hg >> 4, hI = hg & 15;
    const int iq = band * 128 + w * 16 + li;  // this lane's query row
    const int mydiag = 2 * band + (w >> 2);   // this wave's last 64-key tile
    const int ktmax = 2 * band + 1;           // block's last staged tile (>=1)
    const int rowt = 2 * band + (w >> 2);     // wave's 64-row mask tile
    const size_t hoff = (size_t)hg * (2048 * 64);
    const __bf16* qh = qg + hoff;
    const __bf16* kh = kg + hoff;
    const __bf16* vh = vtg + hoff;
    char* pw = (char*)&Ps[w][0];
    const int sw7 = li & 7;

    // Q B-operand frags: qf[half] = Q[iq][32*half + 8g + j]
    bf16x8 qf[2];
#pragma unroll
    for (int half = 0; half < 2; ++half)
        qf[half] = *reinterpret_cast<const bf16x8*>(&qh[(size_t)iq * 64 + half * 32 + g * 8]);

    f32x4 o[4] = {};                          // O[d=16df+4g+r][q=li]
    float mrun = -1e30f, lrun = 0.0f;         // lrun = per-lane partial (own keys)

    // stage one 64-key tile into buffer BUF: K 8KB + V 8KB, 512 thr x 16B each
#define STAGE(BUF, KT) do {                                                       \
    const int p_ = t * 16;                                                        \
    const int row_ = p_ >> 7, sl_ = (p_ >> 4) & 7;                                \
    const int gc_ = (sl_ ^ (row_ & 7)) << 3;                                      \
    async_copy16(kh + (size_t)(((KT) << 6) + row_) * 64 + gc_,                    \
                 (__bf16*)((char*)(&Ks[0][0]) + (BUF) * 8192 + p_));              \
    async_copy16(vh + (size_t)row_ * 2048 + ((KT) << 6) + gc_,                    \
                 (__bf16*)((char*)(&Vs[0][0]) + (BUF) * 8192 + p_));              \
} while (0)

    // prologue: tiles 0,1 in flight; vmcnt(2) -> tile 0 landed; barrier.
    STAGE(0, 0);
    STAGE(1, 1);
    VM2();
    __builtin_amdgcn_s_barrier();

    int cur = 0;
    for (int kt = 0; kt <= ktmax; ++kt) {
        // T4: stage 2 ahead into buffer (cur+2)&3 (tile kt-2's buffer -- all its
        // readers finished before barrier kt-1, already crossed). Counted wait
        // ensures tile kt+1 landed; tile kt was ensured last interval.
        if (kt + 2 <= ktmax) {
            STAGE((cur + 2) & 3, kt + 2);
            VM2();
        } else {
            asm volatile("s_waitcnt vmcnt(0)" ::: "memory");   // tail only
        }
        __builtin_amdgcn_sched_barrier(0);
        __builtin_amdgcn_s_barrier();
        __builtin_amdgcn_sched_barrier(0);
        if (kt <= mydiag) {
            const char* kb = (char*)&Ks[0][0] + cur * 8192;
            const char* vb = (char*)&Vs[0][0] + cur * 8192;
            // ---- S^T = K Q^T : s[kb_][r] = S[key = 64kt+16kb_+4g+r][q = li]
            f32x4 s[4] = {};
            __builtin_amdgcn_s_setprio(1);
#pragma unroll
            for (int kb_ = 0; kb_ < 4; ++kb_) {
                const int row = kb_ * 16 + li;
#pragma unroll
                for (int half = 0; half < 2; ++half) {
                    bf16x8 kf = *reinterpret_cast<const bf16x8*>(
                        kb + row * 128 + (((half * 4 + g) ^ sw7) << 4));
                    s[kb_] = MFMA16(kf, qf[half], s[kb_]);
                }
            }
            __builtin_amdgcn_s_setprio(0);
            // ---- causal / padding mask (diag tile only; pad path never taken here)
            const bool pflag = (mflag[(bI * 32 + rowt) * 32 + kt] == 0);
            if (pflag || kt == mydiag) {
                const int jb = kt * 64;
#pragma unroll
                for (int kb_ = 0; kb_ < 4; ++kb_)
#pragma unroll
                    for (int r = 0; r < 4; ++r) {
                        const int j0 = jb + kb_ * 16 + 4 * g + r;
                        float v0 = s[kb_][r];
                        if (j0 > iq ||
                            (pflag && mask[((size_t)(bI * 2048 + iq)) * 2048 + j0] == 0))
                            v0 = -1e30f;
                        s[kb_][r] = v0;
                    }
            }
            // ---- online softmax, exp2 domain, defer-max (THR=8)
            float mt = fmaxf(fmaxf(s[0][0], s[0][1]), fmaxf(s[0][2], s[0][3]));
#pragma unroll
            for (int kb_ = 1; kb_ < 4; ++kb_)
                mt = fmaxf(mt, fmaxf(fmaxf(s[kb_][0], s[kb_][1]),
                                     fmaxf(s[kb_][2], s[kb_][3])));
            mt = fmaxf(mt, __shfl_xor(mt, 16));
            mt = fmaxf(mt, __shfl_xor(mt, 32));
            if (!__all(mt <= mrun + 8.0f)) {
                const float mn = fmaxf(mrun, mt);
                const float alpha = exp2f(mrun - mn);
#pragma unroll
                for (int df = 0; df < 4; ++df)
#pragma unroll
                    for (int r = 0; r < 4; ++r) o[df][r] *= alpha;
                lrun *= alpha;
                mrun = mn;
            }
#pragma unroll
            for (int kb_ = 0; kb_ < 4; ++kb_)
#pragma unroll
                for (int r = 0; r < 4; ++r) {
                    const float p = exp2f(s[kb_][r] - mrun);
                    s[kb_][r] = p;
                    lrun += p;
                }
            // ---- P -> per-wave LDS (swizzled), lands in PV B-operand layout
#pragma unroll
            for (int kb_ = 0; kb_ < 4; ++kb_) {
                const unsigned lo = packbf(s[kb_][0], s[kb_][1]);
                const unsigned hi = packbf(s[kb_][2], s[kb_][3]);
                *reinterpret_cast<uint2*>(
                    pw + li * 128 + (((2 * kb_ + (g >> 1)) ^ sw7) << 4) + ((g & 1) << 3)) =
                    make_uint2(lo, hi);
            }
            bf16x8 pb[2];
#pragma unroll
            for (int ks = 0; ks < 2; ++ks)
                pb[ks] = *reinterpret_cast<const bf16x8*>(
                    pw + li * 128 + (((4 * ks + g) ^ sw7) << 4));
            // ---- O += V^T P : A = Vt rows (d), 8 MFMA16
            __builtin_amdgcn_s_setprio(1);
#pragma unroll
            for (int df = 0; df < 4; ++df) {
                const int vrow = df * 16 + li;
#pragma unroll
                for (int ks = 0; ks < 2; ++ks) {
                    bf16x8 vf = *reinterpret_cast<const bf16x8*>(
                        vb + vrow * 128 + (((4 * ks + g) ^ sw7) << 4));
                    o[df] = MFMA16(vf, pb[ks], o[df]);
                }
            }
            __builtin_amdgcn_s_setprio(0);
        }
        cur = (cur + 1) & 3;
    }
#undef STAGE

    // ---- epilogue: finish lrun reduction, normalize, write
    lrun += __shfl_xor(lrun, 16);
    lrun += __shfl_xor(lrun, 32);
    const float inv = 1.0f / lrun;
    __bf16* aor = ao + ((size_t)(bI * 2048 + iq)) * 1024 + hI * 64 + g * 4;
#pragma unroll
    for (int df = 0; df < 4; ++df) {
        bf16x4 st;
#pragma unroll
        for (int r = 0; r < 4; ++r) st[r] = (__bf16)(o[df][r] * inv);
        *reinterpret_cast<bf16x4*>(&aor[df * 16]) = st;
    }
}

// ------------------------------- launch -----------------------------------------
extern "C" void kernel_launch(void* const* d_in, const int* in_sizes, int n_in,
                              void* d_out, int out_size, void* d_ws, size_t ws_size,
                              hipStream_t stream)
{
    const float* x      = (const float*)d_in[0];
    const int*   mask   = (const int*)d_in[1];
    const float* qkv_w  = (const float*)d_in[2];
    const float* qkv_b  = (const float*)d_in[3];
    const float* proj_w = (const float*)d_in[4];
    const float* proj_b = (const float*)d_in[5];
    float* out = (float*)d_out;

    char* ws = (char*)d_ws;
    __bf16* xb    = (__bf16*)(ws + 0);          // 4096x1024        8 MB
    __bf16* wqkv  = (__bf16*)(ws + 8388608);    // 3072x1024        6 MB
    __bf16* wproj = (__bf16*)(ws + 14680064);   // 1024x1024        2 MB
    __bf16* qg    = (__bf16*)(ws + 16777216);   // [32,2048,64]     8 MB
    __bf16* kg    = (__bf16*)(ws + 25165824);   // [32,2048,64]     8 MB
    __bf16* vtg   = (__bf16*)(ws + 33554432);   // [32,64,2048]     8 MB
    __bf16* ao    = (__bf16*)(ws + 41943040);   // 4096x1024        8 MB
    int*    mflag = (int*)(ws + 50331648);      // [2,32,32]        4 KB

    // quad counts: 1048576 + 786432 + 262144 = 2097152 -> 8192 blocks x 256
    f32_to_bf16_3k<<<8192, 256, 0, stream>>>(x, xb, 1048576,
                                             qkv_w, wqkv, 786432,
                                             proj_w, wproj, 262144);
    mask_reduce_k<<<2 * 32 * 32, 256, 0, stream>>>(mask, mflag);
    gemm_qkv8_k<<<192, 512, 0, stream>>>(xb, wqkv, qkv_b, qg, kg, vtg);
    attn_k<<<512, 512, 0, stream>>>(qg, kg, vtg, mflag, mask, ao);
    gemm_proj_k<<<32 * 8, 256, 0, stream>>>(ao, wproj, proj_b, 4096, 1024, 1024, out);
}

// Round 12
// 121.364 us; speedup vs baseline: 1.4775x; 1.1055x over previous
//
#include <hip/hip_runtime.h>
#include <hip/hip_bf16.h>

// UnifiedAttention: x->QKV gemm -> causal MHA (H=16,D=64) -> proj gemm
// B=2, N=2048, C=1024. bf16 MFMA with fp32 accum throughout.

typedef __bf16 bf16x8 __attribute__((ext_vector_type(8)));
typedef __bf16 bf16x4 __attribute__((ext_vector_type(4)));
typedef __bf16 bf16x2 __attribute__((ext_vector_type(2)));
typedef float  f32x4  __attribute__((ext_vector_type(4)));
typedef float  f32x16 __attribute__((ext_vector_type(16)));
typedef int    i32x4  __attribute__((ext_vector_type(4)));

#define MFMA16(a, b, c) __builtin_amdgcn_mfma_f32_16x16x32_bf16((a), (b), (c), 0, 0, 0)

__device__ __forceinline__ void async_copy16(const __bf16* g, __bf16* l) {
    __builtin_amdgcn_global_load_lds(
        (const __attribute__((address_space(1))) void*)g,
        (__attribute__((address_space(3))) void*)l,
        16, 0, 0);
}

__device__ __forceinline__ unsigned packbf(float a, float b) {
    union { bf16x2 v; unsigned u; } un;
    un.v[0] = (__bf16)a; un.v[1] = (__bf16)b;
    return un.u;
}

// -------- fp32 -> bf16 conversion, all three tensors in one launch ------------
// counts in float4 QUADS: x 1048576, qkv_w 786432, proj_w 262144 -> 8192 x 256.
__global__ void f32_to_bf16_3k(const float* __restrict__ a, __bf16* __restrict__ ad, int na,
                               const float* __restrict__ b, __bf16* __restrict__ bd, int nb,
                               const float* __restrict__ c, __bf16* __restrict__ cd, int nc)
{
    int i = blockIdx.x * blockDim.x + threadIdx.x;  // quad index
    const float* src; __bf16* dst; int j;
    if (i < na)            { src = a; dst = ad; j = i; }
    else if (i < na + nb)  { src = b; dst = bd; j = i - na; }
    else if (i < na + nb + nc) { src = c; dst = cd; j = i - na - nb; }
    else return;
    float4 v = reinterpret_cast<const float4*>(src)[j];
    bf16x4 o;
    o[0] = (__bf16)v.x; o[1] = (__bf16)v.y; o[2] = (__bf16)v.z; o[3] = (__bf16)v.w;
    reinterpret_cast<bf16x4*>(dst)[j] = o;
}

// ---------------- mask tile reduction: 64x64 tiles -> all-ones flag ----------------
__global__ void mask_reduce_k(const int* __restrict__ mask, int* __restrict__ mflag) {
    __shared__ int ok;
    const int t = threadIdx.x;
    if (t == 0) ok = 1;
    __syncthreads();
    const int jt = blockIdx.x & 31;
    const int it = (blockIdx.x >> 5) & 31;
    const int b  = blockIdx.x >> 10;
    bool all1 = true;
#pragma unroll
    for (int c = 0; c < 4; ++c) {
        const int row = c * 16 + (t >> 4);
        const int col = (t & 15) * 4;
        const int4 v = *reinterpret_cast<const int4*>(
            &mask[((size_t)(b * 2048 + it * 64 + row)) * 2048 + jt * 64 + col]);
        all1 = all1 && v.x && v.y && v.z && v.w;
    }
    if (!all1) ok = 0;
    __syncthreads();
    if (t == 0) mflag[(b * 32 + it) * 32 + jt] = ok;
}

// ============ 8-phase 256x256 QKV GEMM (T1+T2+T3+T4+T5), K=1024 =================
#define BAR() asm volatile("s_barrier" ::: "memory")
#define VM2() asm volatile("s_waitcnt vmcnt(2)" ::: "memory")
#define VM6() asm volatile("s_waitcnt vmcnt(6)" ::: "memory")

__global__ __launch_bounds__(512, 2) void gemm_qkv8_k(
    const __bf16* __restrict__ A, const __bf16* __restrict__ Bm,
    const float* __restrict__ bias,
    __bf16* __restrict__ qg, __bf16* __restrict__ kg, __bf16* __restrict__ vtg)
{
    __shared__ __align__(16) __bf16 As[2][16384];   // [buf][256 rows x 64]
    __shared__ __align__(16) __bf16 Bs[2][16384];

    const int t = threadIdx.x;
    const int lane = t & 63;
    const int w = t >> 6;
    const int wr = w >> 2, wc = w & 3;
    const int li = lane & 15, g = lane >> 4;

    // XCD-aware bijective swizzle (grid=192, 192%8==0, 24 blocks per XCD)
    const int bid = (blockIdx.x & 7) * 24 + (blockIdx.x >> 3);
    const int m0 = (bid / 12) << 8;     // N tiles = 3072/256 = 12
    const int n0 = (bid % 12) << 8;

    const int srow = t >> 3;
    const int scol = ((t & 7) ^ (srow & 7)) << 3;
    const __bf16* pA = A  + (size_t)(m0 + srow) * 1024 + scol;
    const __bf16* pB = Bm + (size_t)(n0 + srow) * 1024 + scol;
    __bf16* dA = &As[0][0] + t * 8;
    __bf16* dB = &Bs[0][0] + t * 8;

#define STAGE_A(BB, T, HH) do {                                                   \
    const size_t ro_ = (size_t)((HH) * 128) * 1024 + (size_t)(T) * 64;            \
    async_copy16(pA + ro_,         dA + (BB) * 16384 + (HH) * 8192);              \
    async_copy16(pA + ro_ + 65536, dA + (BB) * 16384 + (HH) * 8192 + 4096);       \
  } while (0)
#define STAGE_B(BB, T, HH) do {                                                   \
    const size_t ro_ = (size_t)((HH) * 128) * 1024 + (size_t)(T) * 64;            \
    async_copy16(pB + ro_,         dB + (BB) * 16384 + (HH) * 8192);              \
    async_copy16(pB + ro_ + 65536, dB + (BB) * 16384 + (HH) * 8192 + 4096);       \
  } while (0)

    const int aoff0 = ((0 + g) ^ (li & 7)) << 3;
    const int aoff1 = ((4 + g) ^ (li & 7)) << 3;
    const int abase = (wr * 128 + li) * 64;
    const int bbase = (wc * 64 + li) * 64;

    f32x4 acc[8][4] = {};
    bf16x8 a[4][2], b[2][2][2];

#define READ_A(BB, MH) do { _Pragma("unroll")                                     \
    for (int mi2 = 0; mi2 < 4; ++mi2) {                                           \
      const __bf16* p_ = &As[BB][abase + ((MH) * 4 + mi2) * 1024];                \
      a[mi2][0] = *reinterpret_cast<const bf16x8*>(p_ + aoff0);                   \
      a[mi2][1] = *reinterpret_cast<const bf16x8*>(p_ + aoff1); } } while (0)
#define READ_B(BB, NH) do { _Pragma("unroll")                                     \
    for (int ni2 = 0; ni2 < 2; ++ni2) {                                           \
      const __bf16* p_ = &Bs[BB][bbase + ((NH) * 2 + ni2) * 1024];                \
      b[NH][ni2][0] = *reinterpret_cast<const bf16x8*>(p_ + aoff0);               \
      b[NH][ni2][1] = *reinterpret_cast<const bf16x8*>(p_ + aoff1); } } while (0)
#define MFMA_QUAD(MH, NH) do {                                                    \
    __builtin_amdgcn_s_setprio(1);                                                \
    _Pragma("unroll") for (int mi2 = 0; mi2 < 4; ++mi2)                           \
    _Pragma("unroll") for (int ni2 = 0; ni2 < 2; ++ni2) {                         \
      f32x4 c_ = acc[(MH) * 4 + mi2][(NH) * 2 + ni2];                             \
      c_ = MFMA16(a[mi2][0], b[NH][ni2][0], c_);                                  \
      c_ = MFMA16(a[mi2][1], b[NH][ni2][1], c_);                                  \
      acc[(MH) * 4 + mi2][(NH) * 2 + ni2] = c_; }                                 \
    __builtin_amdgcn_s_setprio(0); } while (0)

#define KTILE(BB, T) do {                                                         \
    const int Tn_  = ((T) + 1 < 16) ? (T) + 1 : 15;                               \
    const int Tn2_ = ((T) + 2 < 16) ? (T) + 2 : 15;                               \
    STAGE_A((BB) ^ 1, Tn_, 1);                                                    \
    READ_A(BB, 0); READ_B(BB, 0);                                                 \
    BAR(); MFMA_QUAD(0, 0); BAR();                                                \
    STAGE_B((BB) ^ 1, Tn_, 0);                                                    \
    READ_B(BB, 1);                                                                \
    BAR(); MFMA_QUAD(0, 1); BAR();                                                \
    STAGE_B((BB) ^ 1, Tn_, 1);                                                    \
    READ_A(BB, 1);                                                                \
    BAR(); MFMA_QUAD(1, 0); BAR();                                                \
    STAGE_A((BB), Tn2_, 0);                                                       \
    VM2(); BAR(); MFMA_QUAD(1, 1); BAR();                                         \
  } while (0)

    STAGE_A(0, 0, 0); STAGE_A(0, 0, 1);
    STAGE_B(0, 0, 0); STAGE_B(0, 0, 1);
    STAGE_A(1, 1, 0);
    VM2(); BAR();

#pragma unroll 1
    for (int jj = 0; jj < 8; ++jj) {
        KTILE(0, 2 * jj);
        KTILE(1, 2 * jj + 1);
    }

    // ---- epilogue: scatter into q (scaled by 0.125*log2e for exp2 softmax) / k / vT
    const int nbase = n0 + wc * 64;
    const int s = nbase >> 10;
    const int headg = (m0 >> 11) * 16 + ((nbase & 1023) >> 6);
    const int mrow = (m0 & 2047) + wr * 128 + g * 4;
    float bv[4];
#pragma unroll
    for (int ni = 0; ni < 4; ++ni) bv[ni] = bias[nbase + ni * 16 + li];

    if (s == 2) {
#pragma unroll
        for (int mi = 0; mi < 8; ++mi) {
#pragma unroll
            for (int ni = 0; ni < 4; ++ni) {
                bf16x4 st;
#pragma unroll
                for (int r = 0; r < 4; ++r) st[r] = (__bf16)(acc[mi][ni][r] + bv[ni]);
                *reinterpret_cast<bf16x4*>(
                    &vtg[((size_t)(headg * 64) + ni * 16 + li) * 2048 + mrow + mi * 16]) = st;
            }
        }
    } else {
        __bf16* og = (s == 0) ? qg : kg;
        const float sc = (s == 0) ? 0.18033688f : 1.0f;   // 0.125 * log2(e)
#pragma unroll
        for (int mi = 0; mi < 8; ++mi) {
#pragma unroll
            for (int r = 0; r < 4; ++r) {
                __bf16* rp = og + ((size_t)headg * 2048 + mrow + mi * 16 + r) * 64;
#pragma unroll
                for (int ni = 0; ni < 4; ++ni)
                    rp[ni * 16 + li] = (__bf16)((acc[mi][ni][r] + bv[ni]) * sc);
            }
        }
    }
#undef KTILE
#undef MFMA_QUAD
#undef READ_A
#undef READ_B
#undef STAGE_A
#undef STAGE_B
}

// ------- proj GEMM: 128x64 tile, BK=64, 3-buffer counted-vmcnt (distance-1) -------
// C(4096x1024) = A(4096x1024) * W(1024x1024)^T + bias, fp32 out.
// WAR-safe: STAGE at interval kt writes buf (kt+1)%3, last read by tile kt-2 whose
// readers finished before barrier kt-1 (already crossed). Read-safe: vmcnt(6)
// leaves only tile kt+1's 6 loads outstanding -> tile kt landed.
__global__ __launch_bounds__(256) void gemm_proj_k(
    const __bf16* __restrict__ A, const __bf16* __restrict__ Bm,
    const float* __restrict__ bias, float* __restrict__ outf)
{
    __shared__ __align__(16) __bf16 As[3][8192];   // [buf][128 r x 64], XOR-swz slots
    __shared__ __align__(16) __bf16 Bs[3][4096];   // [buf][64 r x 64], XOR-swz
    const int t = threadIdx.x;
    const int lane = t & 63, w = t >> 6;
    const int li = lane & 15, g = lane >> 4;
    const int wr = w >> 1, wc = w & 1;
    const int sw7 = li & 7;
    // XCD swizzle: 512 blocks, 64/XCD (m-panel locality per XCD)
    const int bid = (blockIdx.x & 7) * 64 + (blockIdx.x >> 3);
    const int m0 = (bid >> 4) << 7;   // 32 m-tiles
    const int n0 = (bid & 15) << 6;   // 16 n-tiles

#define PSTAGE(BUF, KT) do {                                                      \
    _Pragma("unroll")                                                             \
    for (int c_ = 0; c_ < 4; ++c_) {                                              \
        const int row_ = c_ * 32 + (t >> 3);                                      \
        async_copy16(A + (size_t)(m0 + row_) * 1024 + ((KT) << 6)                 \
                       + (((t & 7) ^ (row_ & 7)) << 3),                           \
                     &As[BUF][0] + c_ * 2048 + t * 8);                            \
    }                                                                             \
    _Pragma("unroll")                                                             \
    for (int c_ = 0; c_ < 2; ++c_) {                                              \
        const int row_ = c_ * 32 + (t >> 3);                                      \
        async_copy16(Bm + (size_t)(n0 + row_) * 1024 + ((KT) << 6)                \
                       + (((t & 7) ^ (row_ & 7)) << 3),                           \
                     &Bs[BUF][0] + c_ * 2048 + t * 8);                            \
    }                                                                             \
} while (0)

    f32x4 acc[4][2] = {};

    PSTAGE(0, 0);
    int cur = 0;
    for (int kt = 0; kt < 16; ++kt) {
        int nxt = cur + 1; if (nxt == 3) nxt = 0;
        if (kt < 15) {
            PSTAGE(nxt, kt + 1);
            VM6();
        } else {
            asm volatile("s_waitcnt vmcnt(0)" ::: "memory");
        }
        __builtin_amdgcn_sched_barrier(0);
        __builtin_amdgcn_s_barrier();
        __builtin_amdgcn_sched_barrier(0);

        bf16x8 af[4][2], bf[2][2];
#pragma unroll
        for (int mi = 0; mi < 4; ++mi) {
            const int ra = wr * 64 + mi * 16 + li;
#pragma unroll
            for (int kk = 0; kk < 2; ++kk)
                af[mi][kk] = *reinterpret_cast<const bf16x8*>(
                    (char*)&As[cur][0] + ra * 128 + (((kk * 4 + g) ^ sw7) << 4));
        }
#pragma unroll
        for (int ni = 0; ni < 2; ++ni) {
            const int rb = wc * 32 + ni * 16 + li;
#pragma unroll
            for (int kk = 0; kk < 2; ++kk)
                bf[ni][kk] = *reinterpret_cast<const bf16x8*>(
                    (char*)&Bs[cur][0] + rb * 128 + (((kk * 4 + g) ^ sw7) << 4));
        }
        __builtin_amdgcn_s_setprio(1);
#pragma unroll
        for (int mi = 0; mi < 4; ++mi)
#pragma unroll
            for (int ni = 0; ni < 2; ++ni) {
                f32x4 c_ = acc[mi][ni];
                c_ = MFMA16(af[mi][0], bf[ni][0], c_);
                c_ = MFMA16(af[mi][1], bf[ni][1], c_);
                acc[mi][ni] = c_;
            }
        __builtin_amdgcn_s_setprio(0);
        cur = nxt;
    }
#undef PSTAGE

#pragma unroll
    for (int mi = 0; mi < 4; ++mi) {
#pragma unroll
        for (int ni = 0; ni < 2; ++ni) {
            const int n = n0 + wc * 32 + ni * 16 + li;
            const float bv = bias[n];
#pragma unroll
            for (int r = 0; r < 4; ++r) {
                const int m = m0 + wr * 64 + mi * 16 + g * 4 + r;
                outf[(size_t)m * 1024 + n] = acc[mi][ni][r] + bv;
            }
        }
    }
}

// ------- flash attention, causal: 8 waves x 16q, QUAD-buffer counted-vmcnt --------
// Same as r11 (passing) with ONE change: band pairing balanced across CUs.
// q:[BH,2048,64] (scale*log2e prefolded), k:[BH,2048,64], vT:[BH,64,2048] bf16.
__global__ __launch_bounds__(512) void attn_k(
    const __bf16* __restrict__ qg, const __bf16* __restrict__ kg,
    const __bf16* __restrict__ vtg, const int* __restrict__ mflag,
    const int* __restrict__ mask, __bf16* __restrict__ ao)
{
    __shared__ __align__(16) __bf16 Ks[4][4096];   // [64 keys][64 d], 16B-slot XOR-swz
    __shared__ __align__(16) __bf16 Vs[4][4096];   // [64 d][64 keys], XOR-swz
    __shared__ __align__(16) __bf16 Ps[8][1024];   // per-wave P [16 q][64 keys], XOR-swz
    const int t = threadIdx.x;
    const int w = t >> 6, lane = t & 63;
    const int li = lane & 15, g = lane >> 4;
    // block -> (head-group, band). Balanced pairing: consecutive dispatch windows
    // get bands 15..8 then 0..7, so CU k pairs band (15-q) with band q -> every CU
    // runs a constant 36 tile-intervals (was 48 worst / 20 best: 1.4x makespan).
    const int xcd = blockIdx.x & 7;
    const int idx = blockIdx.x >> 3;          // 0..63
    const int hg  = xcd * 4 + (idx & 3);      // 0..31
    const int q_  = idx >> 2;                 // 0..15
    const int band = (q_ < 8) ? (15 - q_) : (q_ - 8);
    const int bI = hg >> 4, hI = hg & 15;
    const int iq = band * 128 + w * 16 + li;  // this lane's query row
    const int mydiag = 2 * band + (w >> 2);   // this wave's last 64-key tile
    const int ktmax = 2 * band + 1;           // block's last staged tile (>=1)
    const int rowt = 2 * band + (w >> 2);     // wave's 64-row mask tile
    const size_t hoff = (size_t)hg * (2048 * 64);
    const __bf16* qh = qg + hoff;
    const __bf16* kh = kg + hoff;
    const __bf16* vh = vtg + hoff;
    char* pw = (char*)&Ps[w][0];
    const int sw7 = li & 7;

    // Q B-operand frags: qf[half] = Q[iq][32*half + 8g + j]
    bf16x8 qf[2];
#pragma unroll
    for (int half = 0; half < 2; ++half)
        qf[half] = *reinterpret_cast<const bf16x8*>(&qh[(size_t)iq * 64 + half * 32 + g * 8]);

    f32x4 o[4] = {};                          // O[d=16df+4g+r][q=li]
    float mrun = -1e30f, lrun = 0.0f;         // lrun = per-lane partial (own keys)

    // stage one 64-key tile into buffer BUF: K 8KB + V 8KB, 512 thr x 16B each
#define STAGE(BUF, KT) do {                                                       \
    const int p_ = t * 16;                                                        \
    const int row_ = p_ >> 7, sl_ = (p_ >> 4) & 7;                                \
    const int gc_ = (sl_ ^ (row_ & 7)) << 3;                                      \
    async_copy16(kh + (size_t)(((KT) << 6) + row_) * 64 + gc_,                    \
                 (__bf16*)((char*)(&Ks[0][0]) + (BUF) * 8192 + p_));              \
    async_copy16(vh + (size_t)row_ * 2048 + ((KT) << 6) + gc_,                    \
                 (__bf16*)((char*)(&Vs[0][0]) + (BUF) * 8192 + p_));              \
} while (0)

    // prologue: tiles 0,1 in flight; vmcnt(2) -> tile 0 landed; barrier.
    STAGE(0, 0);
    STAGE(1, 1);
    VM2();
    __builtin_amdgcn_s_barrier();

    int cur = 0;
    for (int kt = 0; kt <= ktmax; ++kt) {
        // T4: stage 2 ahead into buffer (cur+2)&3 (tile kt-2's buffer -- all its
        // readers finished before barrier kt-1, already crossed). Counted wait
        // ensures tile kt+1 landed; tile kt was ensured last interval.
        if (kt + 2 <= ktmax) {
            STAGE((cur + 2) & 3, kt + 2);
            VM2();
        } else {
            asm volatile("s_waitcnt vmcnt(0)" ::: "memory");   // tail only
        }
        __builtin_amdgcn_sched_barrier(0);
        __builtin_amdgcn_s_barrier();
        __builtin_amdgcn_sched_barrier(0);
        if (kt <= mydiag) {
            const char* kb = (char*)&Ks[0][0] + cur * 8192;
            const char* vb = (char*)&Vs[0][0] + cur * 8192;
            // ---- S^T = K Q^T : s[kb_][r] = S[key = 64kt+16kb_+4g+r][q = li]
            f32x4 s[4] = {};
            __builtin_amdgcn_s_setprio(1);
#pragma unroll
            for (int kb_ = 0; kb_ < 4; ++kb_) {
                const int row = kb_ * 16 + li;
#pragma unroll
                for (int half = 0; half < 2; ++half) {
                    bf16x8 kf = *reinterpret_cast<const bf16x8*>(
                        kb + row * 128 + (((half * 4 + g) ^ sw7) << 4));
                    s[kb_] = MFMA16(kf, qf[half], s[kb_]);
                }
            }
            __builtin_amdgcn_s_setprio(0);
            // ---- causal / padding mask (diag tile only; pad path never taken here)
            const bool pflag = (mflag[(bI * 32 + rowt) * 32 + kt] == 0);
            if (pflag || kt == mydiag) {
                const int jb = kt * 64;
#pragma unroll
                for (int kb_ = 0; kb_ < 4; ++kb_)
#pragma unroll
                    for (int r = 0; r < 4; ++r) {
                        const int j0 = jb + kb_ * 16 + 4 * g + r;
                        float v0 = s[kb_][r];
                        if (j0 > iq ||
                            (pflag && mask[((size_t)(bI * 2048 + iq)) * 2048 + j0] == 0))
                            v0 = -1e30f;
                        s[kb_][r] = v0;
                    }
            }
            // ---- online softmax, exp2 domain, defer-max (THR=8)
            float mt = fmaxf(fmaxf(s[0][0], s[0][1]), fmaxf(s[0][2], s[0][3]));
#pragma unroll
            for (int kb_ = 1; kb_ < 4; ++kb_)
                mt = fmaxf(mt, fmaxf(fmaxf(s[kb_][0], s[kb_][1]),
                                     fmaxf(s[kb_][2], s[kb_][3])));
            mt = fmaxf(mt, __shfl_xor(mt, 16));
            mt = fmaxf(mt, __shfl_xor(mt, 32));
            if (!__all(mt <= mrun + 8.0f)) {
                const float mn = fmaxf(mrun, mt);
                const float alpha = exp2f(mrun - mn);
#pragma unroll
                for (int df = 0; df < 4; ++df)
#pragma unroll
                    for (int r = 0; r < 4; ++r) o[df][r] *= alpha;
                lrun *= alpha;
                mrun = mn;
            }
#pragma unroll
            for (int kb_ = 0; kb_ < 4; ++kb_)
#pragma unroll
                for (int r = 0; r < 4; ++r) {
                    const float p = exp2f(s[kb_][r] - mrun);
                    s[kb_][r] = p;
                    lrun += p;
                }
            // ---- P -> per-wave LDS (swizzled), lands in PV B-operand layout
#pragma unroll
            for (int kb_ = 0; kb_ < 4; ++kb_) {
                const unsigned lo = packbf(s[kb_][0], s[kb_][1]);
                const unsigned hi = packbf(s[kb_][2], s[kb_][3]);
                *reinterpret_cast<uint2*>(
                    pw + li * 128 + (((2 * kb_ + (g >> 1)) ^ sw7) << 4) + ((g & 1) << 3)) =
                    make_uint2(lo, hi);
            }
            bf16x8 pb[2];
#pragma unroll
            for (int ks = 0; ks < 2; ++ks)
                pb[ks] = *reinterpret_cast<const bf16x8*>(
                    pw + li * 128 + (((4 * ks + g) ^ sw7) << 4));
            // ---- O += V^T P : A = Vt rows (d), 8 MFMA16
            __builtin_amdgcn_s_setprio(1);
#pragma unroll
            for (int df = 0; df < 4; ++df) {
                const int vrow = df * 16 + li;
#pragma unroll
                for (int ks = 0; ks < 2; ++ks) {
                    bf16x8 vf = *reinterpret_cast<const bf16x8*>(
                        vb + vrow * 128 + (((4 * ks + g) ^ sw7) << 4));
                    o[df] = MFMA16(vf, pb[ks], o[df]);
                }
            }
            __builtin_amdgcn_s_setprio(0);
        }
        cur = (cur + 1) & 3;
    }
#undef STAGE

    // ---- epilogue: finish lrun reduction, normalize, write
    lrun += __shfl_xor(lrun, 16);
    lrun += __shfl_xor(lrun, 32);
    const float inv = 1.0f / lrun;
    __bf16* aor = ao + ((size_t)(bI * 2048 + iq)) * 1024 + hI * 64 + g * 4;
#pragma unroll
    for (int df = 0; df < 4; ++df) {
        bf16x4 st;
#pragma unroll
        for (int r = 0; r < 4; ++r) st[r] = (__bf16)(o[df][r] * inv);
        *reinterpret_cast<bf16x4*>(&aor[df * 16]) = st;
    }
}

// ------------------------------- launch -----------------------------------------
extern "C" void kernel_launch(void* const* d_in, const int* in_sizes, int n_in,
                              void* d_out, int out_size, void* d_ws, size_t ws_size,
                              hipStream_t stream)
{
    const float* x      = (const float*)d_in[0];
    const int*   mask   = (const int*)d_in[1];
    const float* qkv_w  = (const float*)d_in[2];
    const float* qkv_b  = (const float*)d_in[3];
    const float* proj_w = (const float*)d_in[4];
    const float* proj_b = (const float*)d_in[5];
    float* out = (float*)d_out;

    char* ws = (char*)d_ws;
    __bf16* xb    = (__bf16*)(ws + 0);          // 4096x1024        8 MB
    __bf16* wqkv  = (__bf16*)(ws + 8388608);    // 3072x1024        6 MB
    __bf16* wproj = (__bf16*)(ws + 14680064);   // 1024x1024        2 MB
    __bf16* qg    = (__bf16*)(ws + 16777216);   // [32,2048,64]     8 MB
    __bf16* kg    = (__bf16*)(ws + 25165824);   // [32,2048,64]     8 MB
    __bf16* vtg   = (__bf16*)(ws + 33554432);   // [32,64,2048]     8 MB
    __bf16* ao    = (__bf16*)(ws + 41943040);   // 4096x1024        8 MB
    int*    mflag = (int*)(ws + 50331648);      // [2,32,32]        4 KB

    // quad counts: 1048576 + 786432 + 262144 = 2097152 -> 8192 blocks x 256
    f32_to_bf16_3k<<<8192, 256, 0, stream>>>(x, xb, 1048576,
                                             qkv_w, wqkv, 786432,
                                             proj_w, wproj, 262144);
    mask_reduce_k<<<2 * 32 * 32, 256, 0, stream>>>(mask, mflag);
    gemm_qkv8_k<<<192, 512, 0, stream>>>(xb, wqkv, qkv_b, qg, kg, vtg);
    attn_k<<<512, 512, 0, stream>>>(qg, kg, vtg, mflag, mask, ao);
    gemm_proj_k<<<512, 256, 0, stream>>>(ao, wproj, proj_b, out);
}